// Round 1
// baseline (744.197 us; speedup 1.0000x reference)
//
#include <hip/hip_runtime.h>

#define N_NODES   10000
#define N_EDGES   50000
#define N_GRAPHS  64
#define NODE_DIM  32
#define EDGE_DIM  16
#define HID       64
#define EHID      128
#define T_STEPS   3
#define S2S_STEPS 6

typedef _Float16 half_t;
typedef _Float16 f16x8 __attribute__((ext_vector_type(8)));
typedef float    f32x4 __attribute__((ext_vector_type(4)));

__device__ __forceinline__ float sigf(float x){ return 1.0f/(1.0f + expf(-x)); }

__global__ void k_zero(float* p, int n){
  int i = blockIdx.x*256 + threadIdx.x;
  if (i < n) p[i] = 0.0f;
}

// h = nf @ W_proj + b_proj   (N x 64)
__global__ void k_proj(const float* __restrict__ nf, const float* __restrict__ Wp,
                       const float* __restrict__ bp, float* __restrict__ h){
  int idx = blockIdx.x*256 + threadIdx.x;
  if (idx >= N_NODES*HID) return;
  int n = idx >> 6;
  int c = idx & 63;
  float acc = bp[c];
  const float* row = nf + (size_t)n*NODE_DIM;
  for (int j = 0; j < NODE_DIM; ++j)
    acc = fmaf(row[j], Wp[j*HID + c], acc);
  h[idx] = acc;
}

// Mm (fp32, fallback path)
__global__ void k_tw2(const float* __restrict__ W2, float* __restrict__ Mm){
  int idx = blockIdx.x*256 + threadIdx.x;
  if (idx >= 64*8192) return;
  int j = idx >> 13; int o = idx & 8191; int k = o >> 6; int i = o & 63;
  Mm[idx] = W2[(size_t)k*4096 + i*64 + j];
}

// BT: W2 in MFMA B-fragment order (fp16), built once.
__global__ void k_w2bt(const float* __restrict__ W2, half_t* __restrict__ BT){
  int idx = blockIdx.x*256 + threadIdx.x;
  if (idx >= 512*2*64*8) return;
  int j    = idx & 7;
  int lane = (idx >> 3) & 63;
  int tk   = (idx >> 9) & 1;
  int tn   = idx >> 10;
  int k = tk*32 + ((lane >> 4) << 3) + j;
  int o = tn*16 + (lane & 15);
  BT[idx] = (half_t)W2[(size_t)(o >> 6)*4096 + (o & 63)*64 + k];
}

// AT: h in MFMA A-fragment order (fp16), per step.
__global__ void k_h2a(const float* __restrict__ h, half_t* __restrict__ AT){
  int idx = blockIdx.x*256 + threadIdx.x;
  if (idx >= 625*2*64*8) return;
  int j    = idx & 7;
  int lane = (idx >> 3) & 63;
  int tk   = (idx >> 9) & 1;
  int tm   = idx >> 10;
  int mrow = tm*16 + (lane & 15);
  int k    = tk*32 + ((lane >> 4) << 3) + j;
  AT[idx] = (half_t)h[(size_t)mrow*64 + k];
}

// GRU weight transposes
__global__ void k_twg(const float* __restrict__ Wg, const float* __restrict__ Wh,
                      float* __restrict__ WgT, float* __restrict__ WhT){
  int idx = blockIdx.x*256 + threadIdx.x;
  if (idx >= 192*64) return;
  int row = idx >> 6;
  int j   = idx & 63;
  WgT[j*192 + row] = Wg[(size_t)row*64 + j];
  WhT[j*192 + row] = Wh[(size_t)row*64 + j];
}

// Folded+transposed LSTM weights: WcT[j][gate], j<64: Wli[:, :64]+Wlh, j>=64: Wli[:, 64:]
// gates = hs @ WcT[0:64] + rs @ WcT[64:128] + bli + blh
__global__ void k_wcT(const float* __restrict__ Wli, const float* __restrict__ Wlh,
                      float* __restrict__ WcT){
  int idx = blockIdx.x*256 + threadIdx.x;
  if (idx >= 128*256) return;
  int j = idx >> 8;      // 0..127
  int g = idx & 255;     // gate
  float v = Wli[(size_t)g*128 + j];
  if (j < 64) v += Wlh[(size_t)g*64 + j];
  WcT[idx] = v;
}

// Hid = relu(ef @ W_e1 + b_e1)  (E x 128) — once per call
__global__ void k_ehid(const float* __restrict__ ef, const float* __restrict__ W1,
                       const float* __restrict__ b1, float* __restrict__ Hid){
  int idx = blockIdx.x*256 + threadIdx.x;
  if (idx >= N_EDGES*EHID) return;
  int e = idx >> 7, c = idx & 127;
  float acc = b1[c];
  const float* er = ef + (size_t)e*EDGE_DIM;
  for (int j = 0; j < EDGE_DIM; ++j)
    acc = fmaf(er[j], W1[j*EHID + c], acc);
  Hid[idx] = fmaxf(acc, 0.0f);
}

// bh[n,i] = sum_j be2[i*64+j] * h[n,j]
__global__ void k_bh(const float* __restrict__ h, const float* __restrict__ be2,
                     float* __restrict__ bh){
  int idx = blockIdx.x*256 + threadIdx.x;
  if (idx >= N_NODES*HID) return;
  int n = idx >> 6, i = idx & 63;
  float acc = 0.0f;
  const float* row = be2 + (size_t)i*64;
  const float* hr  = h + (size_t)n*64;
  for (int j = 0; j < 64; ++j)
    acc = fmaf(row[j], hr[j], acc);
  bh[idx] = acc;
}

// ---- CSR by src ----
__global__ void k_hist(const int* __restrict__ ei, int* __restrict__ deg){
  int e = blockIdx.x*256 + threadIdx.x;
  if (e >= N_EDGES) return;
  atomicAdd(&deg[ei[N_EDGES + e]], 1);
}

__global__ void k_scan(const int* __restrict__ deg, int* __restrict__ rowptr,
                       int* __restrict__ cursor){
  __shared__ int part[256];
  int t = threadIdx.x;
  int base = t*40;
  int s = 0;
  for (int i = 0; i < 40; ++i){
    int idx = base + i;
    if (idx < N_NODES) s += deg[idx];
  }
  part[t] = s;
  __syncthreads();
  for (int off = 1; off < 256; off <<= 1){
    int v = (t >= off) ? part[t - off] : 0;
    __syncthreads();
    part[t] += v;
    __syncthreads();
  }
  int run = (t > 0) ? part[t - 1] : 0;
  for (int i = 0; i < 40; ++i){
    int idx = base + i;
    if (idx < N_NODES){
      rowptr[idx] = run;
      cursor[idx] = run;
      run += deg[idx];
    }
  }
  if (t == 255) rowptr[N_NODES] = run;
}

__global__ void k_scatter(const int* __restrict__ ei, int* __restrict__ cursor,
                          int* __restrict__ csr){
  int e = blockIdx.x*256 + threadIdx.x;
  if (e >= N_EDGES) return;
  int src = ei[N_EDGES + e];
  int pos = atomicAdd(&cursor[src], 1);
  csr[pos] = e;
}

// MFMA C-GEMM (16x16x32_f16): wave = 16 rows x 64 cols, block = 4 waves
__global__ void k_cgemm_mfma(const half_t* __restrict__ AT,
                             const half_t* __restrict__ BT,
                             half_t* __restrict__ C){
  int wv   = threadIdx.x >> 6;
  int lane = threadIdx.x & 63;
  int tm = blockIdx.x*4 + wv;
  if (tm >= 625) return;
  const f16x8* Ab = (const f16x8*)AT + (size_t)tm*128;
  f16x8 a0 = Ab[lane];
  f16x8 a1 = Ab[64 + lane];
  int tn0 = blockIdx.y*4;
  f32x4 acc[4];
  #pragma unroll
  for (int s = 0; s < 4; ++s){ acc[s][0]=0.f; acc[s][1]=0.f; acc[s][2]=0.f; acc[s][3]=0.f; }
  #pragma unroll
  for (int s = 0; s < 4; ++s){
    const f16x8* Bb = (const f16x8*)BT + (size_t)(tn0 + s)*128;
    f16x8 b0 = Bb[lane];
    f16x8 b1 = Bb[64 + lane];
    acc[s] = __builtin_amdgcn_mfma_f32_16x16x32_f16(a0, b0, acc[s], 0, 0, 0);
    acc[s] = __builtin_amdgcn_mfma_f32_16x16x32_f16(a1, b1, acc[s], 0, 0, 0);
  }
  int quad = lane >> 4;
  int colb = lane & 15;
  int mbase = tm*16 + quad*4;
  #pragma unroll
  for (int s = 0; s < 4; ++s){
    size_t cb = (size_t)(tn0 + s)*16 + colb;
    #pragma unroll
    for (int r = 0; r < 4; ++r)
      C[(size_t)(mbase + r)*8192 + cb] = (half_t)acc[s][r];
  }
}

// scalar cgemm (fallback, chunked): 2 cols/thread, fp16 stores
__global__ void k_cgemm(const float* __restrict__ h, const float* __restrict__ Mm,
                        half_t* __restrict__ C, int lo, int hi){
  __shared__ float hs[16][64];
  int n0 = lo + blockIdx.x*16;
  int o0 = blockIdx.y*256 + threadIdx.x;
  for (int idx = threadIdx.x; idx < 16*64; idx += 256){
    int nn = idx >> 6, j = idx & 63;
    int node = n0 + nn;
    hs[nn][j] = (node < hi) ? h[(size_t)node*64 + j] : 0.0f;
  }
  __syncthreads();
  float acc0[16], acc1[16];
  #pragma unroll
  for (int nn = 0; nn < 16; ++nn){ acc0[nn] = 0.0f; acc1[nn] = 0.0f; }
  for (int j4 = 0; j4 < 16; ++j4){
    const float* M0 = Mm + (size_t)(j4*4)*8192;
    float a0 = M0[o0],            b0 = M0[o0 + 4096];
    float a1 = M0[8192 + o0],     b1 = M0[8192 + o0 + 4096];
    float a2 = M0[2*8192 + o0],   b2 = M0[2*8192 + o0 + 4096];
    float a3 = M0[3*8192 + o0],   b3 = M0[3*8192 + o0 + 4096];
    #pragma unroll
    for (int nn = 0; nn < 16; ++nn){
      float4 hv = *(const float4*)&hs[nn][j4*4];
      acc0[nn] = fmaf(hv.x, a0, acc0[nn]);
      acc1[nn] = fmaf(hv.x, b0, acc1[nn]);
      acc0[nn] = fmaf(hv.y, a1, acc0[nn]);
      acc1[nn] = fmaf(hv.y, b1, acc1[nn]);
      acc0[nn] = fmaf(hv.z, a2, acc0[nn]);
      acc1[nn] = fmaf(hv.z, b2, acc1[nn]);
      acc0[nn] = fmaf(hv.w, a3, acc0[nn]);
      acc1[nn] = fmaf(hv.w, b3, acc1[nn]);
    }
  }
  #pragma unroll
  for (int nn = 0; nn < 16; ++nn){
    int node = n0 + nn;
    if (node < hi){
      half_t* Cr = C + (size_t)(node - lo)*8192;
      Cr[o0]        = (half_t)acc0[nn];
      Cr[o0 + 4096] = (half_t)acc1[nn];
    }
  }
}

// One wave per SRC node: stream C[src] row once (fp16), apply to <=8 out-edges
__global__ void MPNN_55705725829535_kernel(const int* __restrict__ rowptr,
                                           const int* __restrict__ csr,
                                           const int* __restrict__ ei,
                                           const float* __restrict__ Hid,
                                           const half_t* __restrict__ C,
                                           const float* __restrict__ bh,
                                           float* __restrict__ m, int lo, int hi){
  __shared__ float hidL[4][8][128];
  int wave = threadIdx.x >> 6;
  int lane = threadIdx.x & 63;
  int s = lo + blockIdx.x*4 + wave;
  if (s >= hi) return;
  int beg = rowptr[s];
  int endp = rowptr[s + 1];
  if (beg == endp) return;
  float bhv = bh[(size_t)s*64 + lane];
  const half_t* Cb = C + (size_t)(s - lo)*8192 + lane;
  float (*hl)[128] = hidL[wave];
  for (int gbeg = beg; gbeg < endp; gbeg += 8){
    int gn = endp - gbeg; if (gn > 8) gn = 8;
    int dsts[8];
    int e0 = csr[gbeg];
    #pragma unroll
    for (int j = 0; j < 8; ++j){
      int e = (j < gn) ? csr[gbeg + j] : e0;
      dsts[j] = ei[e];
      hl[j][lane]      = Hid[(size_t)e*128 + lane];
      hl[j][lane + 64] = Hid[(size_t)e*128 + 64 + lane];
    }
    float acc[8];
    #pragma unroll
    for (int j = 0; j < 8; ++j) acc[j] = 0.0f;
    #pragma unroll 4
    for (int k = 0; k < 128; ++k){
      float c = (float)Cb[k*64];
      #pragma unroll
      for (int j = 0; j < 8; ++j)
        acc[j] = fmaf(hl[j][k], c, acc[j]);
    }
    for (int j = 0; j < gn; ++j)
      atomicAdd(&m[(size_t)dsts[j]*64 + lane], acc[j] + bhv);
  }
}

// fallback per-edge bilinear (only if ws too small for the C path)
__global__ void k_msg_fb(const int* __restrict__ ei, const float* __restrict__ ef,
                         const float* __restrict__ W1, const float* __restrict__ b1,
                         const float* __restrict__ W2, const float* __restrict__ be2,
                         const float* __restrict__ h, float* __restrict__ m){
  __shared__ float HidL[EHID];
  __shared__ __align__(16) float hsL[HID];
  int e = blockIdx.x;
  int t = threadIdx.x;
  int src = ei[N_EDGES + e];
  int dst = ei[e];
  {
    float a0 = b1[t];
    float a1 = b1[t + 64];
    const float* er = ef + (size_t)e*EDGE_DIM;
    for (int j = 0; j < EDGE_DIM; ++j){
      float ev = er[j];
      a0 = fmaf(ev, W1[j*EHID + t],      a0);
      a1 = fmaf(ev, W1[j*EHID + t + 64], a1);
    }
    HidL[t]      = fmaxf(a0, 0.0f);
    HidL[t + 64] = fmaxf(a1, 0.0f);
    hsL[t] = h[(size_t)src*64 + t];
  }
  __syncthreads();
  float acc = 0.0f;
  for (int k = 0; k < EHID; ++k){
    float s = HidL[k];
    if (s != 0.0f){
      const float* w = W2 + (size_t)k*4096 + t*64;
      float partial = 0.0f;
      for (int j = 0; j < 64; ++j)
        partial = fmaf(hsL[j], w[j], partial);
      acc = fmaf(s, partial, acc);
    }
  }
  {
    const float* w = be2 + (size_t)t*64;
    for (int j = 0; j < 64; ++j)
      acc = fmaf(hsL[j], w[j], acc);
  }
  atomicAdd(&m[(size_t)dst*64 + t], acc);
}

// GRU per node, transposed weights
__global__ void k_gru(float* __restrict__ h, const float* __restrict__ m,
                      const float* __restrict__ WgT, const float* __restrict__ WhT,
                      const float* __restrict__ bg, const float* __restrict__ bhb){
  __shared__ float mld[64];
  __shared__ float hld[64];
  int n = blockIdx.x;
  int i = threadIdx.x;
  mld[i] = m[(size_t)n*64 + i];
  hld[i] = h[(size_t)n*64 + i];
  __syncthreads();
  float xr = bg[i],  xz = bg[64 + i],  xn = bg[128 + i];
  float hr = bhb[i], hz = bhb[64 + i], hn = bhb[128 + i];
  for (int j = 0; j < 64; ++j){
    float mj = mld[j];
    float hj = hld[j];
    const float* wg = WgT + j*192;
    const float* wh = WhT + j*192;
    xr = fmaf(mj, wg[i],       xr);
    xz = fmaf(mj, wg[64 + i],  xz);
    xn = fmaf(mj, wg[128 + i], xn);
    hr = fmaf(hj, wh[i],       hr);
    hz = fmaf(hj, wh[64 + i],  hz);
    hn = fmaf(hj, wh[128 + i], hn);
  }
  float r  = sigf(xr + hr);
  float z  = sigf(xz + hz);
  float nn = tanhf(xn + r*hn);
  h[(size_t)n*64 + i] = (1.0f - z)*nn + z*hld[i];
}

// Set2Set + LSTM + readout; 512 threads.
// Gates via folded+transposed WcT[j][gate] (coalesced lane-adjacent reads;
// gate = t&255, half = t>>8 selects hs-part vs rs-part, wave-uniform).
__global__ void k_s2s(const float* __restrict__ h,
                      const float* __restrict__ WcT,
                      const float* __restrict__ bli, const float* __restrict__ blh,
                      const float* __restrict__ Wm1, const float* __restrict__ bm1,
                      const float* __restrict__ Wm2, const float* __restrict__ bm2,
                      float* __restrict__ out){
  __shared__ float hc[157*65];
  __shared__ float ea[160];
  __shared__ float gpart[512];
  __shared__ float rsp[8][64];
  __shared__ float wredA[8];
  __shared__ float wredB[8];
  __shared__ float hsb[64];
  __shared__ float csb[64];
  __shared__ float rsb[64];
  int g = blockIdx.x;
  int t = threadIdx.x;          // 0..511
  int lane = t & 63;
  int wv   = t >> 6;            // 0..7
  int start = (g*N_NODES + 63) >> 6;
  int end   = ((g + 1)*N_NODES + 63) >> 6;
  int cnt = end - start;        // 156 or 157
  const float* hg = h + (size_t)start*64;
  for (int idx = t; idx < cnt*64; idx += 512)
    hc[(idx >> 6)*65 + (idx & 63)] = hg[idx];
  if (t < 64){ hsb[t] = 0.0f; csb[t] = 0.0f; rsb[t] = 0.0f; }
  __syncthreads();
  for (int step = 0; step < S2S_STEPS; ++step){
    float ev = -1e30f;
    if (t < cnt){
      float a = 0.0f;
      const float* hr = &hc[t*65];
      for (int i = 0; i < 64; ++i) a = fmaf(hr[i], hsb[i], a);
      ev = a;
    }
    float v = ev;
    for (int o = 32; o > 0; o >>= 1) v = fmaxf(v, __shfl_xor(v, o));
    if (lane == 0) wredA[wv] = v;
    __syncthreads();                                      // S1
    float mx = wredA[0];
    #pragma unroll
    for (int i = 1; i < 8; ++i) mx = fmaxf(mx, wredA[i]);
    float ex = (t < cnt) ? expf(ev - mx) : 0.0f;
    float sv = ex;
    for (int o = 32; o > 0; o >>= 1) sv += __shfl_xor(sv, o);
    if (lane == 0) wredB[wv] = sv;
    __syncthreads();                                      // S2
    float ssum = 0.0f;
    #pragma unroll
    for (int i = 0; i < 8; ++i) ssum += wredB[i];
    if (t < cnt) ea[t] = ex / (ssum + 1e-16f);
    __syncthreads();                                      // S3
    {
      int n0 = wv*20;
      int n1 = n0 + 20; if (n1 > cnt) n1 = cnt;
      float r = 0.0f;
      for (int n = n0; n < n1; ++n)
        r = fmaf(ea[n], hc[n*65 + lane], r);
      rsp[wv][lane] = r;
    }
    __syncthreads();                                      // S4
    if (t < 64){
      float r = rsp[0][t] + rsp[1][t] + rsp[2][t] + rsp[3][t]
              + rsp[4][t] + rsp[5][t] + rsp[6][t] + rsp[7][t];
      rsb[t] = r;
    }
    __syncthreads();                                      // S5
    {
      // gates[g] = sum_j hs[j]*WcT[j][g] + sum_j rs[j]*WcT[64+j][g]
      // lane-adjacent gates -> coalesced 256B weight loads
      int gate = t & 255;
      int half = t >> 8;           // wave-uniform (waves 0-3 vs 4-7)
      const float* wr = WcT + ((size_t)half*64)*256 + gate;
      float gl = 0.0f;
      if (half == 0){
        #pragma unroll
        for (int jj = 0; jj < 64; ++jj)
          gl = fmaf(hsb[jj], wr[(size_t)jj*256], gl);
      } else {
        #pragma unroll
        for (int jj = 0; jj < 64; ++jj)
          gl = fmaf(rsb[jj], wr[(size_t)jj*256], gl);
      }
      gpart[t] = gl;
    }
    __syncthreads();                                      // S6
    if (t < 64){
      float iv = sigf (gpart[t]       + gpart[t + 256]       + bli[t]       + blh[t]);
      float fv = sigf (gpart[64 + t]  + gpart[64 + t + 256]  + bli[64 + t]  + blh[64 + t]);
      float gv = tanhf(gpart[128 + t] + gpart[128 + t + 256] + bli[128 + t] + blh[128 + t]);
      float ov = sigf (gpart[192 + t] + gpart[192 + t + 256] + bli[192 + t] + blh[192 + t]);
      float c  = fv*csb[t] + iv*gv;
      csb[t] = c;
      hsb[t] = ov*tanhf(c);
    }
    __syncthreads();                                      // S7
  }
  float rv = 0.0f;
  if (t < 64){
    float v = bm1[t];
    for (int j = 0; j < 64; ++j) v = fmaf(hsb[j], Wm1[(size_t)j*64 + t],        v);
    for (int j = 0; j < 64; ++j) v = fmaf(rsb[j], Wm1[(size_t)(64 + j)*64 + t], v);
    v = fmaxf(v, 0.0f);
    rv = v * Wm2[t];
  }
  for (int o = 32; o > 0; o >>= 1) rv += __shfl_xor(rv, o);
  if (lane == 0) wredA[wv] = rv;
  __syncthreads();
  if (t == 0) out[g] = wredA[0] + wredA[1] + wredA[2] + wredA[3]
                     + wredA[4] + wredA[5] + wredA[6] + wredA[7] + bm2[0];
}

extern "C" void kernel_launch(void* const* d_in, const int* in_sizes, int n_in,
                              void* d_out, int out_size, void* d_ws, size_t ws_size,
                              hipStream_t stream){
  (void)in_sizes; (void)n_in; (void)out_size;

  const float* nf  = (const float*)d_in[0];
  const float* ef  = (const float*)d_in[1];
  const int*   ei  = (const int*)d_in[2];
  const float* Wp  = (const float*)d_in[4];
  const float* bp  = (const float*)d_in[5];
  const float* We1 = (const float*)d_in[6];
  const float* be1 = (const float*)d_in[7];
  const float* We2 = (const float*)d_in[8];
  const float* be2 = (const float*)d_in[9];
  const float* Wg  = (const float*)d_in[10];
  const float* Wh  = (const float*)d_in[11];
  const float* bg  = (const float*)d_in[12];
  const float* bhb = (const float*)d_in[13];
  const float* Wli = (const float*)d_in[14];
  const float* Wlh = (const float*)d_in[15];
  const float* bli = (const float*)d_in[16];
  const float* blh = (const float*)d_in[17];
  const float* Wm1 = (const float*)d_in[18];
  const float* bm1 = (const float*)d_in[19];
  const float* Wm2 = (const float*)d_in[20];
  const float* bm2 = (const float*)d_in[21];

  float* out = (float*)d_out;
  float* ws  = (float*)d_ws;

  float* h    = ws;                         //   640000
  float* m    = ws + 640000;                //   640000
  float* bh   = ws + 1280000;               //   640000
  float* Mm   = ws + 1920000;               //   524288  (fallback)
  float* WgT  = ws + 2444288;               //    12288
  float* WhT  = ws + 2456576;               //    12288
  float* Hid  = ws + 2468864;               //  6400000
  int*   deg    = (int*)(ws + 8868864);
  int*   rowptr = deg + 10000;
  int*   cursor = rowptr + 10001;
  int*   csr    = cursor + 10000;
  half_t* AT  = (half_t*)(ws + 8948880);
  half_t* BT  = (half_t*)(ws + 9268880);
  const size_t C_OFF = 9531024;             // floats
  half_t* C   = (half_t*)(ws + C_OFF);

  long long c_halves = ((long long)ws_size - (long long)C_OFF*4) / 2;
  int NC = (c_halves > 0) ? (int)(c_halves / 8192) : 0;
  if (NC > N_NODES) NC = N_NODES;
  int use_c_path = (NC >= 512);
  int use_mfma   = (NC >= N_NODES);

  // WcT (128x256 = 32768 floats) lives in a region unused by the active path:
  //  - mfma path / no-C fallback: Mm region is unused
  //  - scalar-chunk path: AT/BT regions are unused
  float* WcT = (use_c_path && !use_mfma) ? (float*)AT : Mm;

  k_proj<<<(N_NODES*HID + 255)/256, 256, 0, stream>>>(nf, Wp, bp, h);
  k_wcT<<<(128*256 + 255)/256, 256, 0, stream>>>(Wli, Wlh, WcT);

  if (use_c_path){
    k_twg <<<(192*64 + 255)/256, 256, 0, stream>>>(Wg, Wh, WgT, WhT);
    k_ehid<<<(N_EDGES*EHID + 255)/256, 256, 0, stream>>>(ef, We1, be1, Hid);
    k_zero<<<(10000 + 255)/256, 256, 0, stream>>>((float*)deg, 10000);
    k_hist<<<(N_EDGES + 255)/256, 256, 0, stream>>>(ei, deg);
    k_scan<<<1, 256, 0, stream>>>(deg, rowptr, cursor);
    k_scatter<<<(N_EDGES + 255)/256, 256, 0, stream>>>(ei, cursor, csr);
    if (use_mfma){
      k_w2bt<<<(512*2*64*8 + 255)/256, 256, 0, stream>>>(We2, BT);
      for (int step = 0; step < T_STEPS; ++step){
        k_zero<<<(N_NODES*HID + 255)/256, 256, 0, stream>>>(m, N_NODES*HID);
        k_bh<<<(N_NODES*HID + 255)/256, 256, 0, stream>>>(h, be2, bh);
        k_h2a<<<(625*2*64*8 + 255)/256, 256, 0, stream>>>(h, AT);
        dim3 grid(157, 128);
        k_cgemm_mfma<<<grid, 256, 0, stream>>>(AT, BT, C);
        MPNN_55705725829535_kernel<<<(N_NODES + 3)/4, 256, 0, stream>>>(
            rowptr, csr, ei, Hid, C, bh, m, 0, N_NODES);
        k_gru<<<N_NODES, 64, 0, stream>>>(h, m, WgT, WhT, bg, bhb);
      }
    } else {
      k_tw2<<<(64*8192)/256, 256, 0, stream>>>(We2, Mm);
      for (int step = 0; step < T_STEPS; ++step){
        k_zero<<<(N_NODES*HID + 255)/256, 256, 0, stream>>>(m, N_NODES*HID);
        k_bh<<<(N_NODES*HID + 255)/256, 256, 0, stream>>>(h, be2, bh);
        for (int lo = 0; lo < N_NODES; lo += NC){
          int hi = (lo + NC < N_NODES) ? lo + NC : N_NODES;
          int cnt = hi - lo;
          dim3 grid((cnt + 15)/16, 16);
          k_cgemm<<<grid, 256, 0, stream>>>(h, Mm, C, lo, hi);
          MPNN_55705725829535_kernel<<<(cnt + 3)/4, 256, 0, stream>>>(
              rowptr, csr, ei, Hid, C, bh, m, lo, hi);
        }
        k_gru<<<N_NODES, 64, 0, stream>>>(h, m, WgT, WhT, bg, bhb);
      }
    }
  } else {
    k_twg <<<(192*64 + 255)/256, 256, 0, stream>>>(Wg, Wh, WgT, WhT);
    for (int step = 0; step < T_STEPS; ++step){
      k_zero<<<(N_NODES*HID + 255)/256, 256, 0, stream>>>(m, N_NODES*HID);
      k_msg_fb<<<N_EDGES, 64, 0, stream>>>(ei, ef, We1, be1, We2, be2, h, m);
      k_gru<<<N_NODES, 64, 0, stream>>>(h, m, WgT, WhT, bg, bhb);
    }
  }
  k_s2s<<<N_GRAPHS, 512, 0, stream>>>(h, WcT, bli, blh,
                                      Wm1, bm1, Wm2, bm2, out);
}

// Round 2
// 653.029 us; speedup vs baseline: 1.1396x; 1.1396x over previous
//
#include <hip/hip_runtime.h>

#define N_NODES   10000
#define N_EDGES   50000
#define N_GRAPHS  64
#define NODE_DIM  32
#define EDGE_DIM  16
#define HID       64
#define EHID      128
#define T_STEPS   3
#define S2S_STEPS 6

typedef _Float16 half_t;
typedef _Float16 f16x8 __attribute__((ext_vector_type(8)));
typedef float    f32x4 __attribute__((ext_vector_type(4)));

__device__ __forceinline__ float sigf(float x){ return 1.0f/(1.0f + expf(-x)); }

__global__ void k_zero(float* p, int n){
  int i = blockIdx.x*256 + threadIdx.x;
  if (i < n) p[i] = 0.0f;
}

// h = nf @ W_proj + b_proj   (N x 64)
__global__ void k_proj(const float* __restrict__ nf, const float* __restrict__ Wp,
                       const float* __restrict__ bp, float* __restrict__ h){
  int idx = blockIdx.x*256 + threadIdx.x;
  if (idx >= N_NODES*HID) return;
  int n = idx >> 6;
  int c = idx & 63;
  float acc = bp[c];
  const float* row = nf + (size_t)n*NODE_DIM;
  for (int j = 0; j < NODE_DIM; ++j)
    acc = fmaf(row[j], Wp[j*HID + c], acc);
  h[idx] = acc;
}

// Mm (fp32, fallback path)
__global__ void k_tw2(const float* __restrict__ W2, float* __restrict__ Mm){
  int idx = blockIdx.x*256 + threadIdx.x;
  if (idx >= 64*8192) return;
  int j = idx >> 13; int o = idx & 8191; int k = o >> 6; int i = o & 63;
  Mm[idx] = W2[(size_t)k*4096 + i*64 + j];
}

// BT: W2 in MFMA B-fragment order (fp16), built once.
__global__ void k_w2bt(const float* __restrict__ W2, half_t* __restrict__ BT){
  int idx = blockIdx.x*256 + threadIdx.x;
  if (idx >= 512*2*64*8) return;
  int j    = idx & 7;
  int lane = (idx >> 3) & 63;
  int tk   = (idx >> 9) & 1;
  int tn   = idx >> 10;
  int k = tk*32 + ((lane >> 4) << 3) + j;
  int o = tn*16 + (lane & 15);
  BT[idx] = (half_t)W2[(size_t)(o >> 6)*4096 + (o & 63)*64 + k];
}

// AT: h in MFMA A-fragment order (fp16), per step.
__global__ void k_h2a(const float* __restrict__ h, half_t* __restrict__ AT){
  int idx = blockIdx.x*256 + threadIdx.x;
  if (idx >= 625*2*64*8) return;
  int j    = idx & 7;
  int lane = (idx >> 3) & 63;
  int tk   = (idx >> 9) & 1;
  int tm   = idx >> 10;
  int mrow = tm*16 + (lane & 15);
  int k    = tk*32 + ((lane >> 4) << 3) + j;
  AT[idx] = (half_t)h[(size_t)mrow*64 + k];
}

// GRU weight transposes
__global__ void k_twg(const float* __restrict__ Wg, const float* __restrict__ Wh,
                      float* __restrict__ WgT, float* __restrict__ WhT){
  int idx = blockIdx.x*256 + threadIdx.x;
  if (idx >= 192*64) return;
  int row = idx >> 6;
  int j   = idx & 63;
  WgT[j*192 + row] = Wg[(size_t)row*64 + j];
  WhT[j*192 + row] = Wh[(size_t)row*64 + j];
}

// Hid = relu(ef @ W_e1 + b_e1)  (E x 128) — once per call
__global__ void k_ehid(const float* __restrict__ ef, const float* __restrict__ W1,
                       const float* __restrict__ b1, float* __restrict__ Hid){
  int idx = blockIdx.x*256 + threadIdx.x;
  if (idx >= N_EDGES*EHID) return;
  int e = idx >> 7, c = idx & 127;
  float acc = b1[c];
  const float* er = ef + (size_t)e*EDGE_DIM;
  for (int j = 0; j < EDGE_DIM; ++j)
    acc = fmaf(er[j], W1[j*EHID + c], acc);
  Hid[idx] = fmaxf(acc, 0.0f);
}

// bh[n,i] = sum_j be2[i*64+j] * h[n,j]
__global__ void k_bh(const float* __restrict__ h, const float* __restrict__ be2,
                     float* __restrict__ bh){
  int idx = blockIdx.x*256 + threadIdx.x;
  if (idx >= N_NODES*HID) return;
  int n = idx >> 6, i = idx & 63;
  float acc = 0.0f;
  const float* row = be2 + (size_t)i*64;
  const float* hr  = h + (size_t)n*64;
  for (int j = 0; j < 64; ++j)
    acc = fmaf(row[j], hr[j], acc);
  bh[idx] = acc;
}

// ---- CSR by src ----
__global__ void k_hist(const int* __restrict__ ei, int* __restrict__ deg){
  int e = blockIdx.x*256 + threadIdx.x;
  if (e >= N_EDGES) return;
  atomicAdd(&deg[ei[N_EDGES + e]], 1);
}

__global__ void k_scan(const int* __restrict__ deg, int* __restrict__ rowptr,
                       int* __restrict__ cursor){
  __shared__ int part[256];
  int t = threadIdx.x;
  int base = t*40;
  int s = 0;
  for (int i = 0; i < 40; ++i){
    int idx = base + i;
    if (idx < N_NODES) s += deg[idx];
  }
  part[t] = s;
  __syncthreads();
  for (int off = 1; off < 256; off <<= 1){
    int v = (t >= off) ? part[t - off] : 0;
    __syncthreads();
    part[t] += v;
    __syncthreads();
  }
  int run = (t > 0) ? part[t - 1] : 0;
  for (int i = 0; i < 40; ++i){
    int idx = base + i;
    if (idx < N_NODES){
      rowptr[idx] = run;
      cursor[idx] = run;
      run += deg[idx];
    }
  }
  if (t == 255) rowptr[N_NODES] = run;
}

__global__ void k_scatter(const int* __restrict__ ei, int* __restrict__ cursor,
                          int* __restrict__ csr){
  int e = blockIdx.x*256 + threadIdx.x;
  if (e >= N_EDGES) return;
  int src = ei[N_EDGES + e];
  int pos = atomicAdd(&cursor[src], 1);
  csr[pos] = e;
}

// MFMA C-GEMM (16x16x32_f16): wave = 16 rows x 64 cols, block = 4 waves.
// Epilogue: stage fp16 tile in LDS, store full 128B-aligned rows
// (1 dwordx4-equivalent f16x8 store per lane x2) instead of 64 scalar
// 2B stores — avoids partial-line dirty evictions on the 164MB C stream.
__global__ void k_cgemm_mfma(const half_t* __restrict__ AT,
                             const half_t* __restrict__ BT,
                             half_t* __restrict__ C){
  __shared__ half_t tile[4][16][64];
  int wv   = threadIdx.x >> 6;
  int lane = threadIdx.x & 63;
  int tm = blockIdx.x*4 + wv;
  bool active = (tm < 625);
  if (!active) tm = 624;          // keep all waves alive for the barrier
  const f16x8* Ab = (const f16x8*)AT + (size_t)tm*128;
  f16x8 a0 = Ab[lane];
  f16x8 a1 = Ab[64 + lane];
  int tn0 = blockIdx.y*4;
  f32x4 acc[4];
  #pragma unroll
  for (int s = 0; s < 4; ++s){ acc[s][0]=0.f; acc[s][1]=0.f; acc[s][2]=0.f; acc[s][3]=0.f; }
  #pragma unroll
  for (int s = 0; s < 4; ++s){
    const f16x8* Bb = (const f16x8*)BT + (size_t)(tn0 + s)*128;
    f16x8 b0 = Bb[lane];
    f16x8 b1 = Bb[64 + lane];
    acc[s] = __builtin_amdgcn_mfma_f32_16x16x32_f16(a0, b0, acc[s], 0, 0, 0);
    acc[s] = __builtin_amdgcn_mfma_f32_16x16x32_f16(a1, b1, acc[s], 0, 0, 0);
  }
  int quad = lane >> 4;
  int colb = lane & 15;
  #pragma unroll
  for (int s = 0; s < 4; ++s)
    #pragma unroll
    for (int r = 0; r < 4; ++r)
      tile[wv][quad*4 + r][s*16 + colb] = (half_t)acc[s][r];
  __syncthreads();
  if (active){
    int row = lane >> 3;          // 0..7
    int c0  = (lane & 7)*8;       // halves
    size_t base = (size_t)tm*16*8192 + (size_t)tn0*16;
    f16x8 v0 = *(const f16x8*)&tile[wv][row][c0];
    f16x8 v1 = *(const f16x8*)&tile[wv][row + 8][c0];
    *(f16x8*)&C[base + (size_t)row*8192 + c0]       = v0;
    *(f16x8*)&C[base + (size_t)(row + 8)*8192 + c0] = v1;
  }
}

// scalar cgemm (fallback, chunked): 2 cols/thread, fp16 stores
__global__ void k_cgemm(const float* __restrict__ h, const float* __restrict__ Mm,
                        half_t* __restrict__ C, int lo, int hi){
  __shared__ float hs[16][64];
  int n0 = lo + blockIdx.x*16;
  int o0 = blockIdx.y*256 + threadIdx.x;
  for (int idx = threadIdx.x; idx < 16*64; idx += 256){
    int nn = idx >> 6, j = idx & 63;
    int node = n0 + nn;
    hs[nn][j] = (node < hi) ? h[(size_t)node*64 + j] : 0.0f;
  }
  __syncthreads();
  float acc0[16], acc1[16];
  #pragma unroll
  for (int nn = 0; nn < 16; ++nn){ acc0[nn] = 0.0f; acc1[nn] = 0.0f; }
  for (int j4 = 0; j4 < 16; ++j4){
    const float* M0 = Mm + (size_t)(j4*4)*8192;
    float a0 = M0[o0],            b0 = M0[o0 + 4096];
    float a1 = M0[8192 + o0],     b1 = M0[8192 + o0 + 4096];
    float a2 = M0[2*8192 + o0],   b2 = M0[2*8192 + o0 + 4096];
    float a3 = M0[3*8192 + o0],   b3 = M0[3*8192 + o0 + 4096];
    #pragma unroll
    for (int nn = 0; nn < 16; ++nn){
      float4 hv = *(const float4*)&hs[nn][j4*4];
      acc0[nn] = fmaf(hv.x, a0, acc0[nn]);
      acc1[nn] = fmaf(hv.x, b0, acc1[nn]);
      acc0[nn] = fmaf(hv.y, a1, acc0[nn]);
      acc1[nn] = fmaf(hv.y, b1, acc1[nn]);
      acc0[nn] = fmaf(hv.z, a2, acc0[nn]);
      acc1[nn] = fmaf(hv.z, b2, acc1[nn]);
      acc0[nn] = fmaf(hv.w, a3, acc0[nn]);
      acc1[nn] = fmaf(hv.w, b3, acc1[nn]);
    }
  }
  #pragma unroll
  for (int nn = 0; nn < 16; ++nn){
    int node = n0 + nn;
    if (node < hi){
      half_t* Cr = C + (size_t)(node - lo)*8192;
      Cr[o0]        = (half_t)acc0[nn];
      Cr[o0 + 4096] = (half_t)acc1[nn];
    }
  }
}

// One wave per SRC node: stream C[src] row once (fp16), apply to <=8 out-edges
__global__ void MPNN_55705725829535_kernel(const int* __restrict__ rowptr,
                                           const int* __restrict__ csr,
                                           const int* __restrict__ ei,
                                           const float* __restrict__ Hid,
                                           const half_t* __restrict__ C,
                                           const float* __restrict__ bh,
                                           float* __restrict__ m, int lo, int hi){
  __shared__ float hidL[4][8][128];
  int wave = threadIdx.x >> 6;
  int lane = threadIdx.x & 63;
  int s = lo + blockIdx.x*4 + wave;
  if (s >= hi) return;
  int beg = rowptr[s];
  int endp = rowptr[s + 1];
  if (beg == endp) return;
  float bhv = bh[(size_t)s*64 + lane];
  const half_t* Cb = C + (size_t)(s - lo)*8192 + lane;
  float (*hl)[128] = hidL[wave];
  for (int gbeg = beg; gbeg < endp; gbeg += 8){
    int gn = endp - gbeg; if (gn > 8) gn = 8;
    int dsts[8];
    int e0 = csr[gbeg];
    #pragma unroll
    for (int j = 0; j < 8; ++j){
      int e = (j < gn) ? csr[gbeg + j] : e0;
      dsts[j] = ei[e];
      hl[j][lane]      = Hid[(size_t)e*128 + lane];
      hl[j][lane + 64] = Hid[(size_t)e*128 + 64 + lane];
    }
    float acc[8];
    #pragma unroll
    for (int j = 0; j < 8; ++j) acc[j] = 0.0f;
    #pragma unroll 4
    for (int k = 0; k < 128; ++k){
      float c = (float)Cb[k*64];
      #pragma unroll
      for (int j = 0; j < 8; ++j)
        acc[j] = fmaf(hl[j][k], c, acc[j]);
    }
    for (int j = 0; j < gn; ++j)
      atomicAdd(&m[(size_t)dsts[j]*64 + lane], acc[j] + bhv);
  }
}

// fallback per-edge bilinear (only if ws too small for the C path)
__global__ void k_msg_fb(const int* __restrict__ ei, const float* __restrict__ ef,
                         const float* __restrict__ W1, const float* __restrict__ b1,
                         const float* __restrict__ W2, const float* __restrict__ be2,
                         const float* __restrict__ h, float* __restrict__ m){
  __shared__ float HidL[EHID];
  __shared__ __align__(16) float hsL[HID];
  int e = blockIdx.x;
  int t = threadIdx.x;
  int src = ei[N_EDGES + e];
  int dst = ei[e];
  {
    float a0 = b1[t];
    float a1 = b1[t + 64];
    const float* er = ef + (size_t)e*EDGE_DIM;
    for (int j = 0; j < EDGE_DIM; ++j){
      float ev = er[j];
      a0 = fmaf(ev, W1[j*EHID + t],      a0);
      a1 = fmaf(ev, W1[j*EHID + t + 64], a1);
    }
    HidL[t]      = fmaxf(a0, 0.0f);
    HidL[t + 64] = fmaxf(a1, 0.0f);
    hsL[t] = h[(size_t)src*64 + t];
  }
  __syncthreads();
  float acc = 0.0f;
  for (int k = 0; k < EHID; ++k){
    float s = HidL[k];
    if (s != 0.0f){
      const float* w = W2 + (size_t)k*4096 + t*64;
      float partial = 0.0f;
      for (int j = 0; j < 64; ++j)
        partial = fmaf(hsL[j], w[j], partial);
      acc = fmaf(s, partial, acc);
    }
  }
  {
    const float* w = be2 + (size_t)t*64;
    for (int j = 0; j < 64; ++j)
      acc = fmaf(hsL[j], w[j], acc);
  }
  atomicAdd(&m[(size_t)dst*64 + t], acc);
}

// GRU: 256 threads = 4 waves, 16 nodes/block (4 per wave).
// Weight reads are coalesced 256B and amortized over 4 nodes per wave:
// L2 weight traffic 960MB -> 240MB per step.
__global__ void k_gru(float* __restrict__ h, const float* __restrict__ m,
                      const float* __restrict__ WgT, const float* __restrict__ WhT,
                      const float* __restrict__ bg, const float* __restrict__ bhb){
  __shared__ float mld[16][64];
  __shared__ float hld[16][64];
  int t  = threadIdx.x;
  int i  = t & 63;
  int wv = t >> 6;                  // 0..3
  int n0 = blockIdx.x*16;           // 625*16 == 10000 exactly
  for (int idx = t; idx < 16*64; idx += 256){
    int nn = idx >> 6, j = idx & 63;
    int node = n0 + nn;
    mld[nn][j] = m[(size_t)node*64 + j];
    hld[nn][j] = h[(size_t)node*64 + j];
  }
  __syncthreads();
  float xr[4], xz[4], xn[4], hr[4], hz[4], hn[4];
  #pragma unroll
  for (int c = 0; c < 4; ++c){
    xr[c] = bg[i];  xz[c] = bg[64 + i];  xn[c] = bg[128 + i];
    hr[c] = bhb[i]; hz[c] = bhb[64 + i]; hn[c] = bhb[128 + i];
  }
  for (int j = 0; j < 64; ++j){
    const float* wg = WgT + j*192;
    const float* wh = WhT + j*192;
    float wgr = wg[i], wgz = wg[64 + i], wgn = wg[128 + i];
    float whr = wh[i], whz = wh[64 + i], whn = wh[128 + i];
    #pragma unroll
    for (int c = 0; c < 4; ++c){
      int nn = wv*4 + c;
      float mj = mld[nn][j];
      float hj = hld[nn][j];
      xr[c] = fmaf(mj, wgr, xr[c]);
      xz[c] = fmaf(mj, wgz, xz[c]);
      xn[c] = fmaf(mj, wgn, xn[c]);
      hr[c] = fmaf(hj, whr, hr[c]);
      hz[c] = fmaf(hj, whz, hz[c]);
      hn[c] = fmaf(hj, whn, hn[c]);
    }
  }
  #pragma unroll
  for (int c = 0; c < 4; ++c){
    int nn = wv*4 + c;
    float r  = sigf(xr[c] + hr[c]);
    float z  = sigf(xz[c] + hz[c]);
    float nv = tanhf(xn[c] + r*hn[c]);
    h[(size_t)(n0 + nn)*64 + i] = (1.0f - z)*nv + z*hld[nn][i];
  }
}

// Set2Set + LSTM + readout; 512 threads: rsb 8-way split, gates 2-way split.
// Direct Wli/Wlh reads (L1-resident per-thread rows — proven faster than
// transposed at 1-block/CU occupancy; r1's coalesced-WcT variant REGRESSED
// 56->95us: per-thread sequential rows vectorize to dwordx4 and L1-hit,
// the 1KB-stride coalesced layout missed L1 on every load).
__global__ void k_s2s(const float* __restrict__ h,
                      const float* __restrict__ Wli, const float* __restrict__ Wlh,
                      const float* __restrict__ bli, const float* __restrict__ blh,
                      const float* __restrict__ Wm1, const float* __restrict__ bm1,
                      const float* __restrict__ Wm2, const float* __restrict__ bm2,
                      float* __restrict__ out){
  __shared__ float hc[157*65];
  __shared__ float ea[160];
  __shared__ float x[192];
  __shared__ float gpart[512];
  __shared__ float rsp[8][64];
  __shared__ float wredA[8];
  __shared__ float wredB[8];
  __shared__ float hsb[64];
  __shared__ float csb[64];
  __shared__ float rsb[64];
  int g = blockIdx.x;
  int t = threadIdx.x;          // 0..511
  int lane = t & 63;
  int wv   = t >> 6;            // 0..7
  int start = (g*N_NODES + 63) >> 6;
  int end   = ((g + 1)*N_NODES + 63) >> 6;
  int cnt = end - start;        // 156 or 157
  const float* hg = h + (size_t)start*64;
  for (int idx = t; idx < cnt*64; idx += 512)
    hc[(idx >> 6)*65 + (idx & 63)] = hg[idx];
  if (t < 64){ hsb[t] = 0.0f; csb[t] = 0.0f; rsb[t] = 0.0f; }
  __syncthreads();
  for (int step = 0; step < S2S_STEPS; ++step){
    float ev = -1e30f;
    if (t < cnt){
      float a = 0.0f;
      const float* hr = &hc[t*65];
      for (int i = 0; i < 64; ++i) a = fmaf(hr[i], hsb[i], a);
      ev = a;
    }
    float v = ev;
    for (int o = 32; o > 0; o >>= 1) v = fmaxf(v, __shfl_xor(v, o));
    if (lane == 0) wredA[wv] = v;
    __syncthreads();                                      // S1
    float mx = wredA[0];
    #pragma unroll
    for (int i = 1; i < 8; ++i) mx = fmaxf(mx, wredA[i]);
    float ex = (t < cnt) ? expf(ev - mx) : 0.0f;
    float sv = ex;
    for (int o = 32; o > 0; o >>= 1) sv += __shfl_xor(sv, o);
    if (lane == 0) wredB[wv] = sv;
    __syncthreads();                                      // S2
    float ssum = 0.0f;
    #pragma unroll
    for (int i = 0; i < 8; ++i) ssum += wredB[i];
    if (t < cnt) ea[t] = ex / (ssum + 1e-16f);
    __syncthreads();                                      // S3
    {
      int n0 = wv*20;
      int n1 = n0 + 20; if (n1 > cnt) n1 = cnt;
      float r = 0.0f;
      for (int n = n0; n < n1; ++n)
        r = fmaf(ea[n], hc[n*65 + lane], r);
      rsp[wv][lane] = r;
    }
    __syncthreads();                                      // S4
    if (t < 64){
      float r = rsp[0][t] + rsp[1][t] + rsp[2][t] + rsp[3][t]
              + rsp[4][t] + rsp[5][t] + rsp[6][t] + rsp[7][t];
      rsb[t] = r;
      x[t]        = hsb[t];
      x[64 + t]   = r;
      x[128 + t]  = hsb[t];
    }
    __syncthreads();                                      // S5
    {
      int gate = t & 255;
      int half = t >> 8;
      float gl = 0.0f;
      if (half == 0){
        const float* wr = Wli + (size_t)gate*128;
        for (int jj = 0; jj < 96; ++jj) gl = fmaf(x[jj], wr[jj], gl);
      } else {
        const float* wr = Wli + (size_t)gate*128;
        for (int jj = 96; jj < 128; ++jj) gl = fmaf(x[jj], wr[jj], gl);
        const float* wh = Wlh + (size_t)gate*64;
        for (int jj = 0; jj < 64; ++jj) gl = fmaf(x[128 + jj], wh[jj], gl);
      }
      gpart[t] = gl;
    }
    __syncthreads();                                      // S6
    if (t < 64){
      float iv = sigf (gpart[t]       + gpart[t + 256]       + bli[t]       + blh[t]);
      float fv = sigf (gpart[64 + t]  + gpart[64 + t + 256]  + bli[64 + t]  + blh[64 + t]);
      float gv = tanhf(gpart[128 + t] + gpart[128 + t + 256] + bli[128 + t] + blh[128 + t]);
      float ov = sigf (gpart[192 + t] + gpart[192 + t + 256] + bli[192 + t] + blh[192 + t]);
      float c  = fv*csb[t] + iv*gv;
      csb[t] = c;
      hsb[t] = ov*tanhf(c);
    }
    __syncthreads();                                      // S7
  }
  float rv = 0.0f;
  if (t < 64){
    float v = bm1[t];
    for (int j = 0; j < 64; ++j) v = fmaf(hsb[j], Wm1[(size_t)j*64 + t],        v);
    for (int j = 0; j < 64; ++j) v = fmaf(rsb[j], Wm1[(size_t)(64 + j)*64 + t], v);
    v = fmaxf(v, 0.0f);
    rv = v * Wm2[t];
  }
  for (int o = 32; o > 0; o >>= 1) rv += __shfl_xor(rv, o);
  if (lane == 0) wredA[wv] = rv;
  __syncthreads();
  if (t == 0) out[g] = wredA[0] + wredA[1] + wredA[2] + wredA[3]
                     + wredA[4] + wredA[5] + wredA[6] + wredA[7] + bm2[0];
}

extern "C" void kernel_launch(void* const* d_in, const int* in_sizes, int n_in,
                              void* d_out, int out_size, void* d_ws, size_t ws_size,
                              hipStream_t stream){
  (void)in_sizes; (void)n_in; (void)out_size;

  const float* nf  = (const float*)d_in[0];
  const float* ef  = (const float*)d_in[1];
  const int*   ei  = (const int*)d_in[2];
  const float* Wp  = (const float*)d_in[4];
  const float* bp  = (const float*)d_in[5];
  const float* We1 = (const float*)d_in[6];
  const float* be1 = (const float*)d_in[7];
  const float* We2 = (const float*)d_in[8];
  const float* be2 = (const float*)d_in[9];
  const float* Wg  = (const float*)d_in[10];
  const float* Wh  = (const float*)d_in[11];
  const float* bg  = (const float*)d_in[12];
  const float* bhb = (const float*)d_in[13];
  const float* Wli = (const float*)d_in[14];
  const float* Wlh = (const float*)d_in[15];
  const float* bli = (const float*)d_in[16];
  const float* blh = (const float*)d_in[17];
  const float* Wm1 = (const float*)d_in[18];
  const float* bm1 = (const float*)d_in[19];
  const float* Wm2 = (const float*)d_in[20];
  const float* bm2 = (const float*)d_in[21];

  float* out = (float*)d_out;
  float* ws  = (float*)d_ws;

  float* h    = ws;                         //   640000
  float* m    = ws + 640000;                //   640000
  float* bh   = ws + 1280000;               //   640000
  float* Mm   = ws + 1920000;               //   524288  (fallback)
  float* WgT  = ws + 2444288;               //    12288
  float* WhT  = ws + 2456576;               //    12288
  float* Hid  = ws + 2468864;               //  6400000
  int*   deg    = (int*)(ws + 8868864);
  int*   rowptr = deg + 10000;
  int*   cursor = rowptr + 10001;
  int*   csr    = cursor + 10000;
  half_t* AT  = (half_t*)(ws + 8948880);
  half_t* BT  = (half_t*)(ws + 9268880);
  const size_t C_OFF = 9531024;             // floats
  half_t* C   = (half_t*)(ws + C_OFF);

  long long c_halves = ((long long)ws_size - (long long)C_OFF*4) / 2;
  int NC = (c_halves > 0) ? (int)(c_halves / 8192) : 0;
  if (NC > N_NODES) NC = N_NODES;
  int use_c_path = (NC >= 512);
  int use_mfma   = (NC >= N_NODES);

  k_proj<<<(N_NODES*HID + 255)/256, 256, 0, stream>>>(nf, Wp, bp, h);

  if (use_c_path){
    k_twg <<<(192*64 + 255)/256, 256, 0, stream>>>(Wg, Wh, WgT, WhT);
    k_ehid<<<(N_EDGES*EHID + 255)/256, 256, 0, stream>>>(ef, We1, be1, Hid);
    k_zero<<<(10000 + 255)/256, 256, 0, stream>>>((float*)deg, 10000);
    k_hist<<<(N_EDGES + 255)/256, 256, 0, stream>>>(ei, deg);
    k_scan<<<1, 256, 0, stream>>>(deg, rowptr, cursor);
    k_scatter<<<(N_EDGES + 255)/256, 256, 0, stream>>>(ei, cursor, csr);
    if (use_mfma){
      k_w2bt<<<(512*2*64*8 + 255)/256, 256, 0, stream>>>(We2, BT);
      for (int step = 0; step < T_STEPS; ++step){
        k_zero<<<(N_NODES*HID + 255)/256, 256, 0, stream>>>(m, N_NODES*HID);
        k_bh<<<(N_NODES*HID + 255)/256, 256, 0, stream>>>(h, be2, bh);
        k_h2a<<<(625*2*64*8 + 255)/256, 256, 0, stream>>>(h, AT);
        dim3 grid(157, 128);
        k_cgemm_mfma<<<grid, 256, 0, stream>>>(AT, BT, C);
        MPNN_55705725829535_kernel<<<(N_NODES + 3)/4, 256, 0, stream>>>(
            rowptr, csr, ei, Hid, C, bh, m, 0, N_NODES);
        k_gru<<<625, 256, 0, stream>>>(h, m, WgT, WhT, bg, bhb);
      }
    } else {
      k_tw2<<<(64*8192)/256, 256, 0, stream>>>(We2, Mm);
      for (int step = 0; step < T_STEPS; ++step){
        k_zero<<<(N_NODES*HID + 255)/256, 256, 0, stream>>>(m, N_NODES*HID);
        k_bh<<<(N_NODES*HID + 255)/256, 256, 0, stream>>>(h, be2, bh);
        for (int lo = 0; lo < N_NODES; lo += NC){
          int hi = (lo + NC < N_NODES) ? lo + NC : N_NODES;
          int cnt = hi - lo;
          dim3 grid((cnt + 15)/16, 16);
          k_cgemm<<<grid, 256, 0, stream>>>(h, Mm, C, lo, hi);
          MPNN_55705725829535_kernel<<<(cnt + 3)/4, 256, 0, stream>>>(
              rowptr, csr, ei, Hid, C, bh, m, lo, hi);
        }
        k_gru<<<625, 256, 0, stream>>>(h, m, WgT, WhT, bg, bhb);
      }
    }
  } else {
    k_twg <<<(192*64 + 255)/256, 256, 0, stream>>>(Wg, Wh, WgT, WhT);
    for (int step = 0; step < T_STEPS; ++step){
      k_zero<<<(N_NODES*HID + 255)/256, 256, 0, stream>>>(m, N_NODES*HID);
      k_msg_fb<<<N_EDGES, 64, 0, stream>>>(ei, ef, We1, be1, We2, be2, h, m);
      k_gru<<<625, 256, 0, stream>>>(h, m, WgT, WhT, bg, bhb);
    }
  }
  k_s2s<<<N_GRAPHS, 512, 0, stream>>>(h, Wli, Wlh, bli, blh,
                                      Wm1, bm1, Wm2, bm2, out);
}

// Round 3
// 613.772 us; speedup vs baseline: 1.2125x; 1.0640x over previous
//
#include <hip/hip_runtime.h>

#define N_NODES   10000
#define N_EDGES   50000
#define N_GRAPHS  64
#define NODE_DIM  32
#define EDGE_DIM  16
#define HID       64
#define EHID      128
#define T_STEPS   3
#define S2S_STEPS 6

typedef _Float16 half_t;
typedef _Float16 f16x8 __attribute__((ext_vector_type(8)));
typedef float    f32x4 __attribute__((ext_vector_type(4)));

__device__ __forceinline__ float sigf(float x){ return 1.0f/(1.0f + expf(-x)); }

__global__ void k_zero(float* p, int n){
  int i = blockIdx.x*256 + threadIdx.x;
  if (i < n) p[i] = 0.0f;
}

// h = nf @ W_proj + b_proj   (N x 64)
__global__ void k_proj(const float* __restrict__ nf, const float* __restrict__ Wp,
                       const float* __restrict__ bp, float* __restrict__ h){
  int idx = blockIdx.x*256 + threadIdx.x;
  if (idx >= N_NODES*HID) return;
  int n = idx >> 6;
  int c = idx & 63;
  float acc = bp[c];
  const float* row = nf + (size_t)n*NODE_DIM;
  for (int j = 0; j < NODE_DIM; ++j)
    acc = fmaf(row[j], Wp[j*HID + c], acc);
  h[idx] = acc;
}

// Mm (fp32, fallback path)
__global__ void k_tw2(const float* __restrict__ W2, float* __restrict__ Mm){
  int idx = blockIdx.x*256 + threadIdx.x;
  if (idx >= 64*8192) return;
  int j = idx >> 13; int o = idx & 8191; int k = o >> 6; int i = o & 63;
  Mm[idx] = W2[(size_t)k*4096 + i*64 + j];
}

// BT: W2 in MFMA B-fragment order (fp16), built once.
// BT[tno][tk][lane][j] : contraction k = tk*32 + (lane>>4)*8 + j (h-feature),
// output col o = tno*16 + (lane&15), o = k_edge*64 + i.
__global__ void k_w2bt(const float* __restrict__ W2, half_t* __restrict__ BT){
  int idx = blockIdx.x*256 + threadIdx.x;
  if (idx >= 512*2*64*8) return;
  int j    = idx & 7;
  int lane = (idx >> 3) & 63;
  int tk   = (idx >> 9) & 1;
  int tn   = idx >> 10;
  int k = tk*32 + ((lane >> 4) << 3) + j;
  int o = tn*16 + (lane & 15);
  BT[idx] = (half_t)W2[(size_t)(o >> 6)*4096 + (o & 63)*64 + k];
}

// AT: h in MFMA A-fragment order (fp16), per step.
__global__ void k_h2a(const float* __restrict__ h, half_t* __restrict__ AT){
  int idx = blockIdx.x*256 + threadIdx.x;
  if (idx >= 625*2*64*8) return;
  int j    = idx & 7;
  int lane = (idx >> 3) & 63;
  int tk   = (idx >> 9) & 1;
  int tm   = idx >> 10;
  int mrow = tm*16 + (lane & 15);
  int k    = tk*32 + ((lane >> 4) << 3) + j;
  AT[idx] = (half_t)h[(size_t)mrow*64 + k];
}

// GRU weight transposes
__global__ void k_twg(const float* __restrict__ Wg, const float* __restrict__ Wh,
                      float* __restrict__ WgT, float* __restrict__ WhT){
  int idx = blockIdx.x*256 + threadIdx.x;
  if (idx >= 192*64) return;
  int row = idx >> 6;
  int j   = idx & 63;
  WgT[j*192 + row] = Wg[(size_t)row*64 + j];
  WhT[j*192 + row] = Wh[(size_t)row*64 + j];
}

// Hid = relu(ef @ W_e1 + b_e1)  fp32 (fallback path)
__global__ void k_ehid(const float* __restrict__ ef, const float* __restrict__ W1,
                       const float* __restrict__ b1, float* __restrict__ Hid){
  int idx = blockIdx.x*256 + threadIdx.x;
  if (idx >= N_EDGES*EHID) return;
  int e = idx >> 7, c = idx & 127;
  float acc = b1[c];
  const float* er = ef + (size_t)e*EDGE_DIM;
  for (int j = 0; j < EDGE_DIM; ++j)
    acc = fmaf(er[j], W1[j*EHID + c], acc);
  Hid[idx] = fmaxf(acc, 0.0f);
}

// Hid16 = relu(ef @ W_e1 + b_e1) in fp16 (MFMA message path)
__global__ void k_ehid16(const float* __restrict__ ef, const float* __restrict__ W1,
                         const float* __restrict__ b1, half_t* __restrict__ Hid16){
  int idx = blockIdx.x*256 + threadIdx.x;
  if (idx >= N_EDGES*EHID) return;
  int e = idx >> 7, c = idx & 127;
  float acc = b1[c];
  const float* er = ef + (size_t)e*EDGE_DIM;
  for (int j = 0; j < EDGE_DIM; ++j)
    acc = fmaf(er[j], W1[j*EHID + c], acc);
  Hid16[idx] = (half_t)fmaxf(acc, 0.0f);
}

// bh[n,i] = sum_j be2[i*64+j] * h[n,j]
__global__ void k_bh(const float* __restrict__ h, const float* __restrict__ be2,
                     float* __restrict__ bh){
  int idx = blockIdx.x*256 + threadIdx.x;
  if (idx >= N_NODES*HID) return;
  int n = idx >> 6, i = idx & 63;
  float acc = 0.0f;
  const float* row = be2 + (size_t)i*64;
  const float* hr  = h + (size_t)n*64;
  for (int j = 0; j < 64; ++j)
    acc = fmaf(row[j], hr[j], acc);
  bh[idx] = acc;
}

// ---- CSR by src ----
__global__ void k_hist(const int* __restrict__ ei, int* __restrict__ deg){
  int e = blockIdx.x*256 + threadIdx.x;
  if (e >= N_EDGES) return;
  atomicAdd(&deg[ei[N_EDGES + e]], 1);
}

__global__ void k_scan(const int* __restrict__ deg, int* __restrict__ rowptr,
                       int* __restrict__ cursor){
  __shared__ int part[256];
  int t = threadIdx.x;
  int base = t*40;
  int s = 0;
  for (int i = 0; i < 40; ++i){
    int idx = base + i;
    if (idx < N_NODES) s += deg[idx];
  }
  part[t] = s;
  __syncthreads();
  for (int off = 1; off < 256; off <<= 1){
    int v = (t >= off) ? part[t - off] : 0;
    __syncthreads();
    part[t] += v;
    __syncthreads();
  }
  int run = (t > 0) ? part[t - 1] : 0;
  for (int i = 0; i < 40; ++i){
    int idx = base + i;
    if (idx < N_NODES){
      rowptr[idx] = run;
      cursor[idx] = run;
      run += deg[idx];
    }
  }
  if (t == 255) rowptr[N_NODES] = run;
}

__global__ void k_scatter(const int* __restrict__ ei, int* __restrict__ cursor,
                          int* __restrict__ csr){
  int e = blockIdx.x*256 + threadIdx.x;
  if (e >= N_EDGES) return;
  int src = ei[N_EDGES + e];
  int pos = atomicAdd(&cursor[src], 1);
  csr[pos] = e;
}

// MFMA C-GEMM producing C in per-node B-fragment layout:
//   C[n][kt][isub][L][j]  (halves)  addr = n*8192 + kt*2048 + isub*512 + L*8 + j
//   where for element (k_edge, i): kt=k_edge>>5, k_in=k_edge&31,
//   L = (k_in>>3)*16 + (i&15), j = k_in&7, isub = i>>4.
// grid (625 tm, 4 kt), 4 waves; wave wv handles k_in = wv*8 + jj (jj 0..7).
// Epilogue packs the 8 jj values (adjacent halves) into one f16x8 store:
// 8 lanes x 16B = full 128B lines, no LDS.
__global__ void k_cgemm_mfma(const half_t* __restrict__ AT,
                             const half_t* __restrict__ BT,
                             half_t* __restrict__ C){
  int wv   = threadIdx.x >> 6;    // = Lhi
  int lane = threadIdx.x & 63;
  int tm   = blockIdx.x;          // 0..624
  int kt   = blockIdx.y;          // 0..3
  const f16x8* Ab = (const f16x8*)AT + (size_t)tm*128;
  f16x8 a0 = Ab[lane];
  f16x8 a1 = Ab[64 + lane];
  f32x4 acc[4][8];
  #pragma unroll
  for (int is = 0; is < 4; ++is)
    #pragma unroll
    for (int jj = 0; jj < 8; ++jj){
      acc[is][jj][0]=0.f; acc[is][jj][1]=0.f; acc[is][jj][2]=0.f; acc[is][jj][3]=0.f;
    }
  #pragma unroll
  for (int jj = 0; jj < 8; ++jj){
    int ke = kt*32 + wv*8 + jj;               // k_edge
    const f16x8* Bb = (const f16x8*)BT + (size_t)(ke*4)*128 + lane;
    #pragma unroll
    for (int is = 0; is < 4; ++is){
      f16x8 b0 = Bb[is*128];
      f16x8 b1 = Bb[is*128 + 64];
      acc[is][jj] = __builtin_amdgcn_mfma_f32_16x16x32_f16(a0, b0, acc[is][jj], 0, 0, 0);
      acc[is][jj] = __builtin_amdgcn_mfma_f32_16x16x32_f16(a1, b1, acc[is][jj], 0, 0, 0);
    }
  }
  int quad = lane >> 4;
  int colb = lane & 15;
  #pragma unroll
  for (int r = 0; r < 4; ++r){
    int n = tm*16 + quad*4 + r;
    #pragma unroll
    for (int is = 0; is < 4; ++is){
      f16x8 v;
      #pragma unroll
      for (int jj = 0; jj < 8; ++jj) v[jj] = (half_t)acc[is][jj][r];
      *(f16x8*)&C[(size_t)n*8192 + kt*2048 + is*512 + (size_t)(wv*16 + colb)*8] = v;
    }
  }
}

// scalar cgemm (fallback, chunked): 2 cols/thread, fp16 stores, OLD linear C layout
__global__ void k_cgemm(const float* __restrict__ h, const float* __restrict__ Mm,
                        half_t* __restrict__ C, int lo, int hi){
  __shared__ float hs[16][64];
  int n0 = lo + blockIdx.x*16;
  int o0 = blockIdx.y*256 + threadIdx.x;
  for (int idx = threadIdx.x; idx < 16*64; idx += 256){
    int nn = idx >> 6, j = idx & 63;
    int node = n0 + nn;
    hs[nn][j] = (node < hi) ? h[(size_t)node*64 + j] : 0.0f;
  }
  __syncthreads();
  float acc0[16], acc1[16];
  #pragma unroll
  for (int nn = 0; nn < 16; ++nn){ acc0[nn] = 0.0f; acc1[nn] = 0.0f; }
  for (int j4 = 0; j4 < 16; ++j4){
    const float* M0 = Mm + (size_t)(j4*4)*8192;
    float a0 = M0[o0],            b0 = M0[o0 + 4096];
    float a1 = M0[8192 + o0],     b1 = M0[8192 + o0 + 4096];
    float a2 = M0[2*8192 + o0],   b2 = M0[2*8192 + o0 + 4096];
    float a3 = M0[3*8192 + o0],   b3 = M0[3*8192 + o0 + 4096];
    #pragma unroll
    for (int nn = 0; nn < 16; ++nn){
      float4 hv = *(const float4*)&hs[nn][j4*4];
      acc0[nn] = fmaf(hv.x, a0, acc0[nn]);
      acc1[nn] = fmaf(hv.x, b0, acc1[nn]);
      acc0[nn] = fmaf(hv.y, a1, acc0[nn]);
      acc1[nn] = fmaf(hv.y, b1, acc1[nn]);
      acc0[nn] = fmaf(hv.z, a2, acc0[nn]);
      acc1[nn] = fmaf(hv.z, b2, acc1[nn]);
      acc0[nn] = fmaf(hv.w, a3, acc0[nn]);
      acc1[nn] = fmaf(hv.w, b3, acc1[nn]);
    }
  }
  #pragma unroll
  for (int nn = 0; nn < 16; ++nn){
    int node = n0 + nn;
    if (node < hi){
      half_t* Cr = C + (size_t)(node - lo)*8192;
      Cr[o0]        = (half_t)acc0[nn];
      Cr[o0 + 4096] = (half_t)acc1[nn];
    }
  }
}

// MFMA message kernel: one wave per SRC node.
// msgs(<=16 edges x 64) = Hid16(edges x 128) @ C[src](128 x 64) via 16 MFMA.
// B-frags from C's per-node fragment layout: f16x8 at lane*16B (coalesced).
// A-frags gathered from Hid16 rows (16B per lane). Replaces 128 scalar loads
// + 1024 LDS broadcasts + 1024 VALU FMA per wave of the old kernel.
__global__ void MPNN_55705725829535_kernel(const int* __restrict__ rowptr,
                                           const int* __restrict__ csr,
                                           const int* __restrict__ ei,
                                           const half_t* __restrict__ Hid16,
                                           const half_t* __restrict__ C,
                                           const float* __restrict__ bh,
                                           float* __restrict__ m){
  __shared__ int dstL[4][16];
  int wave = threadIdx.x >> 6;
  int lane = threadIdx.x & 63;
  int s = blockIdx.x*4 + wave;
  if (s >= N_NODES) return;
  int beg  = rowptr[s];
  int endp = rowptr[s + 1];
  if (beg == endp) return;
  int quad = lane >> 4;
  int colb = lane & 15;
  // B-fragments of C[s] (16 loads, lane-coalesced)
  const f16x8* Cb = (const f16x8*)(C + (size_t)s*8192) + lane;
  f16x8 B[4][4];
  #pragma unroll
  for (int kt = 0; kt < 4; ++kt)
    #pragma unroll
    for (int is = 0; is < 4; ++is)
      B[kt][is] = Cb[kt*256 + is*64];
  float bhc[4];
  #pragma unroll
  for (int is = 0; is < 4; ++is)
    bhc[is] = bh[(size_t)s*64 + is*16 + colb];
  for (int gbeg = beg; gbeg < endp; gbeg += 16){
    int gn = endp - gbeg; if (gn > 16) gn = 16;
    if (lane < 16)
      dstL[wave][lane] = (lane < gn) ? ei[csr[gbeg + lane]] : -1;
    // A-fragments: row = lane&15 = edge slot, k = kt*32 + (lane>>4)*8 + j
    f16x8 A[4];
    if (colb < gn){
      int e = csr[gbeg + colb];
      const f16x8* Hb = (const f16x8*)(Hid16 + (size_t)e*128) + quad;
      #pragma unroll
      for (int kt = 0; kt < 4; ++kt)
        A[kt] = Hb[kt*4];
    } else {
      #pragma unroll
      for (int kt = 0; kt < 4; ++kt)
        #pragma unroll
        for (int q = 0; q < 8; ++q) A[kt][q] = (half_t)0;
    }
    f32x4 acc[4];
    #pragma unroll
    for (int is = 0; is < 4; ++is){
      acc[is][0]=0.f; acc[is][1]=0.f; acc[is][2]=0.f; acc[is][3]=0.f;
    }
    #pragma unroll
    for (int kt = 0; kt < 4; ++kt)
      #pragma unroll
      for (int is = 0; is < 4; ++is)
        acc[is] = __builtin_amdgcn_mfma_f32_16x16x32_f16(A[kt], B[kt][is], acc[is], 0, 0, 0);
    // scatter: row j = quad*4 + r, col = is*16 + colb
    #pragma unroll
    for (int r = 0; r < 4; ++r){
      int jrow = quad*4 + r;
      if (jrow < gn){
        int d = dstL[wave][jrow];
        float* mr = m + (size_t)d*64 + colb;
        #pragma unroll
        for (int is = 0; is < 4; ++is)
          atomicAdd(mr + is*16, acc[is][r] + bhc[is]);
      }
    }
  }
}

// old-style streaming msg kernel (fallback path, fp32 Hid, OLD linear C layout)
__global__ void k_msg_csr(const int* __restrict__ rowptr,
                          const int* __restrict__ csr,
                          const int* __restrict__ ei,
                          const float* __restrict__ Hid,
                          const half_t* __restrict__ C,
                          const float* __restrict__ bh,
                          float* __restrict__ m, int lo, int hi){
  __shared__ float hidL[4][8][128];
  int wave = threadIdx.x >> 6;
  int lane = threadIdx.x & 63;
  int s = lo + blockIdx.x*4 + wave;
  if (s >= hi) return;
  int beg = rowptr[s];
  int endp = rowptr[s + 1];
  if (beg == endp) return;
  float bhv = bh[(size_t)s*64 + lane];
  const half_t* Cb = C + (size_t)(s - lo)*8192 + lane;
  float (*hl)[128] = hidL[wave];
  for (int gbeg = beg; gbeg < endp; gbeg += 8){
    int gn = endp - gbeg; if (gn > 8) gn = 8;
    int dsts[8];
    int e0 = csr[gbeg];
    #pragma unroll
    for (int j = 0; j < 8; ++j){
      int e = (j < gn) ? csr[gbeg + j] : e0;
      dsts[j] = ei[e];
      hl[j][lane]      = Hid[(size_t)e*128 + lane];
      hl[j][lane + 64] = Hid[(size_t)e*128 + 64 + lane];
    }
    float acc[8];
    #pragma unroll
    for (int j = 0; j < 8; ++j) acc[j] = 0.0f;
    #pragma unroll 4
    for (int k = 0; k < 128; ++k){
      float c = (float)Cb[k*64];
      #pragma unroll
      for (int j = 0; j < 8; ++j)
        acc[j] = fmaf(hl[j][k], c, acc[j]);
    }
    for (int j = 0; j < gn; ++j)
      atomicAdd(&m[(size_t)dsts[j]*64 + lane], acc[j] + bhv);
  }
}

// fallback per-edge bilinear (only if ws too small for the C path)
__global__ void k_msg_fb(const int* __restrict__ ei, const float* __restrict__ ef,
                         const float* __restrict__ W1, const float* __restrict__ b1,
                         const float* __restrict__ W2, const float* __restrict__ be2,
                         const float* __restrict__ h, float* __restrict__ m){
  __shared__ float HidL[EHID];
  __shared__ __align__(16) float hsL[HID];
  int e = blockIdx.x;
  int t = threadIdx.x;
  int src = ei[N_EDGES + e];
  int dst = ei[e];
  {
    float a0 = b1[t];
    float a1 = b1[t + 64];
    const float* er = ef + (size_t)e*EDGE_DIM;
    for (int j = 0; j < EDGE_DIM; ++j){
      float ev = er[j];
      a0 = fmaf(ev, W1[j*EHID + t],      a0);
      a1 = fmaf(ev, W1[j*EHID + t + 64], a1);
    }
    HidL[t]      = fmaxf(a0, 0.0f);
    HidL[t + 64] = fmaxf(a1, 0.0f);
    hsL[t] = h[(size_t)src*64 + t];
  }
  __syncthreads();
  float acc = 0.0f;
  for (int k = 0; k < EHID; ++k){
    float s = HidL[k];
    if (s != 0.0f){
      const float* w = W2 + (size_t)k*4096 + t*64;
      float partial = 0.0f;
      for (int j = 0; j < 64; ++j)
        partial = fmaf(hsL[j], w[j], partial);
      acc = fmaf(s, partial, acc);
    }
  }
  {
    const float* w = be2 + (size_t)t*64;
    for (int j = 0; j < 64; ++j)
      acc = fmaf(hsL[j], w[j], acc);
  }
  atomicAdd(&m[(size_t)dst*64 + t], acc);
}

// GRU: 256 threads = 4 waves, 16 nodes/block (4 per wave).
__global__ void k_gru(float* __restrict__ h, const float* __restrict__ m,
                      const float* __restrict__ WgT, const float* __restrict__ WhT,
                      const float* __restrict__ bg, const float* __restrict__ bhb){
  __shared__ float mld[16][64];
  __shared__ float hld[16][64];
  int t  = threadIdx.x;
  int i  = t & 63;
  int wv = t >> 6;                  // 0..3
  int n0 = blockIdx.x*16;           // 625*16 == 10000 exactly
  for (int idx = t; idx < 16*64; idx += 256){
    int nn = idx >> 6, j = idx & 63;
    int node = n0 + nn;
    mld[nn][j] = m[(size_t)node*64 + j];
    hld[nn][j] = h[(size_t)node*64 + j];
  }
  __syncthreads();
  float xr[4], xz[4], xn[4], hr[4], hz[4], hn[4];
  #pragma unroll
  for (int c = 0; c < 4; ++c){
    xr[c] = bg[i];  xz[c] = bg[64 + i];  xn[c] = bg[128 + i];
    hr[c] = bhb[i]; hz[c] = bhb[64 + i]; hn[c] = bhb[128 + i];
  }
  for (int j = 0; j < 64; ++j){
    const float* wg = WgT + j*192;
    const float* wh = WhT + j*192;
    float wgr = wg[i], wgz = wg[64 + i], wgn = wg[128 + i];
    float whr = wh[i], whz = wh[64 + i], whn = wh[128 + i];
    #pragma unroll
    for (int c = 0; c < 4; ++c){
      int nn = wv*4 + c;
      float mj = mld[nn][j];
      float hj = hld[nn][j];
      xr[c] = fmaf(mj, wgr, xr[c]);
      xz[c] = fmaf(mj, wgz, xz[c]);
      xn[c] = fmaf(mj, wgn, xn[c]);
      hr[c] = fmaf(hj, whr, hr[c]);
      hz[c] = fmaf(hj, whz, hz[c]);
      hn[c] = fmaf(hj, whn, hn[c]);
    }
  }
  #pragma unroll
  for (int c = 0; c < 4; ++c){
    int nn = wv*4 + c;
    float r  = sigf(xr[c] + hr[c]);
    float z  = sigf(xz[c] + hz[c]);
    float nv = tanhf(xn[c] + r*hn[c]);
    h[(size_t)(n0 + nn)*64 + i] = (1.0f - z)*nv + z*hld[nn][i];
  }
}

// Set2Set + LSTM + readout; 512 threads: rsb 8-way split, gates 2-way split.
// Direct Wli/Wlh reads (per-thread sequential rows vectorize to dwordx4 and
// L1-hit; r1's coalesced-WcT layout REGRESSED 56->95us — do not retry).
__global__ void k_s2s(const float* __restrict__ h,
                      const float* __restrict__ Wli, const float* __restrict__ Wlh,
                      const float* __restrict__ bli, const float* __restrict__ blh,
                      const float* __restrict__ Wm1, const float* __restrict__ bm1,
                      const float* __restrict__ Wm2, const float* __restrict__ bm2,
                      float* __restrict__ out){
  __shared__ float hc[157*65];
  __shared__ float ea[160];
  __shared__ float x[192];
  __shared__ float gpart[512];
  __shared__ float rsp[8][64];
  __shared__ float wredA[8];
  __shared__ float wredB[8];
  __shared__ float hsb[64];
  __shared__ float csb[64];
  __shared__ float rsb[64];
  int g = blockIdx.x;
  int t = threadIdx.x;          // 0..511
  int lane = t & 63;
  int wv   = t >> 6;            // 0..7
  int start = (g*N_NODES + 63) >> 6;
  int end   = ((g + 1)*N_NODES + 63) >> 6;
  int cnt = end - start;        // 156 or 157
  const float* hg = h + (size_t)start*64;
  for (int idx = t; idx < cnt*64; idx += 512)
    hc[(idx >> 6)*65 + (idx & 63)] = hg[idx];
  if (t < 64){ hsb[t] = 0.0f; csb[t] = 0.0f; rsb[t] = 0.0f; }
  __syncthreads();
  for (int step = 0; step < S2S_STEPS; ++step){
    float ev = -1e30f;
    if (t < cnt){
      float a = 0.0f;
      const float* hr = &hc[t*65];
      for (int i = 0; i < 64; ++i) a = fmaf(hr[i], hsb[i], a);
      ev = a;
    }
    float v = ev;
    for (int o = 32; o > 0; o >>= 1) v = fmaxf(v, __shfl_xor(v, o));
    if (lane == 0) wredA[wv] = v;
    __syncthreads();                                      // S1
    float mx = wredA[0];
    #pragma unroll
    for (int i = 1; i < 8; ++i) mx = fmaxf(mx, wredA[i]);
    float ex = (t < cnt) ? expf(ev - mx) : 0.0f;
    float sv = ex;
    for (int o = 32; o > 0; o >>= 1) sv += __shfl_xor(sv, o);
    if (lane == 0) wredB[wv] = sv;
    __syncthreads();                                      // S2
    float ssum = 0.0f;
    #pragma unroll
    for (int i = 0; i < 8; ++i) ssum += wredB[i];
    if (t < cnt) ea[t] = ex / (ssum + 1e-16f);
    __syncthreads();                                      // S3
    {
      int n0 = wv*20;
      int n1 = n0 + 20; if (n1 > cnt) n1 = cnt;
      float r = 0.0f;
      for (int n = n0; n < n1; ++n)
        r = fmaf(ea[n], hc[n*65 + lane], r);
      rsp[wv][lane] = r;
    }
    __syncthreads();                                      // S4
    if (t < 64){
      float r = rsp[0][t] + rsp[1][t] + rsp[2][t] + rsp[3][t]
              + rsp[4][t] + rsp[5][t] + rsp[6][t] + rsp[7][t];
      rsb[t] = r;
      x[t]        = hsb[t];
      x[64 + t]   = r;
      x[128 + t]  = hsb[t];
    }
    __syncthreads();                                      // S5
    {
      int gate = t & 255;
      int half = t >> 8;
      float gl = 0.0f;
      if (half == 0){
        const float* wr = Wli + (size_t)gate*128;
        for (int jj = 0; jj < 96; ++jj) gl = fmaf(x[jj], wr[jj], gl);
      } else {
        const float* wr = Wli + (size_t)gate*128;
        for (int jj = 96; jj < 128; ++jj) gl = fmaf(x[jj], wr[jj], gl);
        const float* wh = Wlh + (size_t)gate*64;
        for (int jj = 0; jj < 64; ++jj) gl = fmaf(x[128 + jj], wh[jj], gl);
      }
      gpart[t] = gl;
    }
    __syncthreads();                                      // S6
    if (t < 64){
      float iv = sigf (gpart[t]       + gpart[t + 256]       + bli[t]       + blh[t]);
      float fv = sigf (gpart[64 + t]  + gpart[64 + t + 256]  + bli[64 + t]  + blh[64 + t]);
      float gv = tanhf(gpart[128 + t] + gpart[128 + t + 256] + bli[128 + t] + blh[128 + t]);
      float ov = sigf (gpart[192 + t] + gpart[192 + t + 256] + bli[192 + t] + blh[192 + t]);
      float c  = fv*csb[t] + iv*gv;
      csb[t] = c;
      hsb[t] = ov*tanhf(c);
    }
    __syncthreads();                                      // S7
  }
  float rv = 0.0f;
  if (t < 64){
    float v = bm1[t];
    for (int j = 0; j < 64; ++j) v = fmaf(hsb[j], Wm1[(size_t)j*64 + t],        v);
    for (int j = 0; j < 64; ++j) v = fmaf(rsb[j], Wm1[(size_t)(64 + j)*64 + t], v);
    v = fmaxf(v, 0.0f);
    rv = v * Wm2[t];
  }
  for (int o = 32; o > 0; o >>= 1) rv += __shfl_xor(rv, o);
  if (lane == 0) wredA[wv] = rv;
  __syncthreads();
  if (t == 0) out[g] = wredA[0] + wredA[1] + wredA[2] + wredA[3]
                     + wredA[4] + wredA[5] + wredA[6] + wredA[7] + bm2[0];
}

extern "C" void kernel_launch(void* const* d_in, const int* in_sizes, int n_in,
                              void* d_out, int out_size, void* d_ws, size_t ws_size,
                              hipStream_t stream){
  (void)in_sizes; (void)n_in; (void)out_size;

  const float* nf  = (const float*)d_in[0];
  const float* ef  = (const float*)d_in[1];
  const int*   ei  = (const int*)d_in[2];
  const float* Wp  = (const float*)d_in[4];
  const float* bp  = (const float*)d_in[5];
  const float* We1 = (const float*)d_in[6];
  const float* be1 = (const float*)d_in[7];
  const float* We2 = (const float*)d_in[8];
  const float* be2 = (const float*)d_in[9];
  const float* Wg  = (const float*)d_in[10];
  const float* Wh  = (const float*)d_in[11];
  const float* bg  = (const float*)d_in[12];
  const float* bhb = (const float*)d_in[13];
  const float* Wli = (const float*)d_in[14];
  const float* Wlh = (const float*)d_in[15];
  const float* bli = (const float*)d_in[16];
  const float* blh = (const float*)d_in[17];
  const float* Wm1 = (const float*)d_in[18];
  const float* bm1 = (const float*)d_in[19];
  const float* Wm2 = (const float*)d_in[20];
  const float* bm2 = (const float*)d_in[21];

  float* out = (float*)d_out;
  float* ws  = (float*)d_ws;

  float* h    = ws;                         //   640000
  float* m    = ws + 640000;                //   640000
  float* bh   = ws + 1280000;               //   640000
  float* Mm   = ws + 1920000;               //   524288  (fallback)
  float* WgT  = ws + 2444288;               //    12288
  float* WhT  = ws + 2456576;               //    12288
  float* Hid  = ws + 2468864;               //  6400000 (fp32 fallback / fp16 main)
  half_t* Hid16 = (half_t*)Hid;
  int*   deg    = (int*)(ws + 8868864);
  int*   rowptr = deg + 10000;
  int*   cursor = rowptr + 10001;
  int*   csr    = cursor + 10000;
  half_t* AT  = (half_t*)(ws + 8948880);
  half_t* BT  = (half_t*)(ws + 9268880);
  const size_t C_OFF = 9531024;             // floats
  half_t* C   = (half_t*)(ws + C_OFF);

  long long c_halves = ((long long)ws_size - (long long)C_OFF*4) / 2;
  int NC = (c_halves > 0) ? (int)(c_halves / 8192) : 0;
  if (NC > N_NODES) NC = N_NODES;
  int use_c_path = (NC >= 512);
  int use_mfma   = (NC >= N_NODES);

  k_proj<<<(N_NODES*HID + 255)/256, 256, 0, stream>>>(nf, Wp, bp, h);

  if (use_c_path){
    k_twg <<<(192*64 + 255)/256, 256, 0, stream>>>(Wg, Wh, WgT, WhT);
    k_zero<<<(10000 + 255)/256, 256, 0, stream>>>((float*)deg, 10000);
    k_hist<<<(N_EDGES + 255)/256, 256, 0, stream>>>(ei, deg);
    k_scan<<<1, 256, 0, stream>>>(deg, rowptr, cursor);
    k_scatter<<<(N_EDGES + 255)/256, 256, 0, stream>>>(ei, cursor, csr);
    if (use_mfma){
      k_ehid16<<<(N_EDGES*EHID + 255)/256, 256, 0, stream>>>(ef, We1, be1, Hid16);
      k_w2bt<<<(512*2*64*8 + 255)/256, 256, 0, stream>>>(We2, BT);
      for (int step = 0; step < T_STEPS; ++step){
        k_zero<<<(N_NODES*HID + 255)/256, 256, 0, stream>>>(m, N_NODES*HID);
        k_bh<<<(N_NODES*HID + 255)/256, 256, 0, stream>>>(h, be2, bh);
        k_h2a<<<(625*2*64*8 + 255)/256, 256, 0, stream>>>(h, AT);
        dim3 grid(625, 4);
        k_cgemm_mfma<<<grid, 256, 0, stream>>>(AT, BT, C);
        MPNN_55705725829535_kernel<<<(N_NODES + 3)/4, 256, 0, stream>>>(
            rowptr, csr, ei, Hid16, C, bh, m);
        k_gru<<<625, 256, 0, stream>>>(h, m, WgT, WhT, bg, bhb);
      }
    } else {
      k_ehid<<<(N_EDGES*EHID + 255)/256, 256, 0, stream>>>(ef, We1, be1, Hid);
      k_tw2<<<(64*8192)/256, 256, 0, stream>>>(We2, Mm);
      for (int step = 0; step < T_STEPS; ++step){
        k_zero<<<(N_NODES*HID + 255)/256, 256, 0, stream>>>(m, N_NODES*HID);
        k_bh<<<(N_NODES*HID + 255)/256, 256, 0, stream>>>(h, be2, bh);
        for (int lo = 0; lo < N_NODES; lo += NC){
          int hi = (lo + NC < N_NODES) ? lo + NC : N_NODES;
          int cnt = hi - lo;
          dim3 grid((cnt + 15)/16, 16);
          k_cgemm<<<grid, 256, 0, stream>>>(h, Mm, C, lo, hi);
          k_msg_csr<<<(cnt + 3)/4, 256, 0, stream>>>(
              rowptr, csr, ei, Hid, C, bh, m, lo, hi);
        }
        k_gru<<<625, 256, 0, stream>>>(h, m, WgT, WhT, bg, bhb);
      }
    }
  } else {
    k_twg <<<(192*64 + 255)/256, 256, 0, stream>>>(Wg, Wh, WgT, WhT);
    for (int step = 0; step < T_STEPS; ++step){
      k_zero<<<(N_NODES*HID + 255)/256, 256, 0, stream>>>(m, N_NODES*HID);
      k_msg_fb<<<N_EDGES, 64, 0, stream>>>(ei, ef, We1, be1, We2, be2, h, m);
      k_gru<<<625, 256, 0, stream>>>(h, m, WgT, WhT, bg, bhb);
    }
  }
  k_s2s<<<N_GRAPHS, 512, 0, stream>>>(h, Wli, Wlh, bli, blh,
                                      Wm1, bm1, Wm2, bm2, out);
}

// Round 4
// 601.184 us; speedup vs baseline: 1.2379x; 1.0209x over previous
//
#include <hip/hip_runtime.h>

#define N_NODES   10000
#define N_EDGES   50000
#define N_GRAPHS  64
#define NODE_DIM  32
#define EDGE_DIM  16
#define HID       64
#define EHID      128
#define T_STEPS   3
#define S2S_STEPS 6

typedef _Float16 half_t;
typedef _Float16 f16x8 __attribute__((ext_vector_type(8)));
typedef float    f32x4 __attribute__((ext_vector_type(4)));

__device__ __forceinline__ float sigf(float x){ return 1.0f/(1.0f + expf(-x)); }

__global__ void k_zero(float* p, int n){
  int i = blockIdx.x*256 + threadIdx.x;
  if (i < n) p[i] = 0.0f;
}

// h = nf @ W_proj + b_proj   (N x 64)
__global__ void k_proj(const float* __restrict__ nf, const float* __restrict__ Wp,
                       const float* __restrict__ bp, float* __restrict__ h){
  int idx = blockIdx.x*256 + threadIdx.x;
  if (idx >= N_NODES*HID) return;
  int n = idx >> 6;
  int c = idx & 63;
  float acc = bp[c];
  const float* row = nf + (size_t)n*NODE_DIM;
  for (int j = 0; j < NODE_DIM; ++j)
    acc = fmaf(row[j], Wp[j*HID + c], acc);
  h[idx] = acc;
}

// Mm (fp32, fallback path)
__global__ void k_tw2(const float* __restrict__ W2, float* __restrict__ Mm){
  int idx = blockIdx.x*256 + threadIdx.x;
  if (idx >= 64*8192) return;
  int j = idx >> 13; int o = idx & 8191; int k = o >> 6; int i = o & 63;
  Mm[idx] = W2[(size_t)k*4096 + i*64 + j];
}

// BT: W2 in MFMA B-fragment order (fp16), built once.
// BT[tn][tk][lane][j] : contraction k = tk*32 + (lane>>4)*8 + j (h-feature),
// output col o = tn*16 + (lane&15), o = k_edge*64 + i.
__global__ void k_w2bt(const float* __restrict__ W2, half_t* __restrict__ BT){
  int idx = blockIdx.x*256 + threadIdx.x;
  if (idx >= 512*2*64*8) return;
  int j    = idx & 7;
  int lane = (idx >> 3) & 63;
  int tk   = (idx >> 9) & 1;
  int tn   = idx >> 10;
  int k = tk*32 + ((lane >> 4) << 3) + j;
  int o = tn*16 + (lane & 15);
  BT[idx] = (half_t)W2[(size_t)(o >> 6)*4096 + (o & 63)*64 + k];
}

// AT: h in MFMA A-fragment order (fp16), per step.
__global__ void k_h2a(const float* __restrict__ h, half_t* __restrict__ AT){
  int idx = blockIdx.x*256 + threadIdx.x;
  if (idx >= 625*2*64*8) return;
  int j    = idx & 7;
  int lane = (idx >> 3) & 63;
  int tk   = (idx >> 9) & 1;
  int tm   = idx >> 10;
  int mrow = tm*16 + (lane & 15);
  int k    = tk*32 + ((lane >> 4) << 3) + j;
  AT[idx] = (half_t)h[(size_t)mrow*64 + k];
}

// GRU weight transposes
__global__ void k_twg(const float* __restrict__ Wg, const float* __restrict__ Wh,
                      float* __restrict__ WgT, float* __restrict__ WhT){
  int idx = blockIdx.x*256 + threadIdx.x;
  if (idx >= 192*64) return;
  int row = idx >> 6;
  int j   = idx & 63;
  WgT[j*192 + row] = Wg[(size_t)row*64 + j];
  WhT[j*192 + row] = Wh[(size_t)row*64 + j];
}

// Hid = relu(ef @ W_e1 + b_e1)  fp32 (fallback path)
__global__ void k_ehid(const float* __restrict__ ef, const float* __restrict__ W1,
                       const float* __restrict__ b1, float* __restrict__ Hid){
  int idx = blockIdx.x*256 + threadIdx.x;
  if (idx >= N_EDGES*EHID) return;
  int e = idx >> 7, c = idx & 127;
  float acc = b1[c];
  const float* er = ef + (size_t)e*EDGE_DIM;
  for (int j = 0; j < EDGE_DIM; ++j)
    acc = fmaf(er[j], W1[j*EHID + c], acc);
  Hid[idx] = fmaxf(acc, 0.0f);
}

// Hid16 = relu(ef @ W_e1 + b_e1) in fp16 (MFMA message path)
__global__ void k_ehid16(const float* __restrict__ ef, const float* __restrict__ W1,
                         const float* __restrict__ b1, half_t* __restrict__ Hid16){
  int idx = blockIdx.x*256 + threadIdx.x;
  if (idx >= N_EDGES*EHID) return;
  int e = idx >> 7, c = idx & 127;
  float acc = b1[c];
  const float* er = ef + (size_t)e*EDGE_DIM;
  for (int j = 0; j < EDGE_DIM; ++j)
    acc = fmaf(er[j], W1[j*EHID + c], acc);
  Hid16[idx] = (half_t)fmaxf(acc, 0.0f);
}

// bh[n,i] = sum_j be2[i*64+j] * h[n,j]
__global__ void k_bh(const float* __restrict__ h, const float* __restrict__ be2,
                     float* __restrict__ bh){
  int idx = blockIdx.x*256 + threadIdx.x;
  if (idx >= N_NODES*HID) return;
  int n = idx >> 6, i = idx & 63;
  float acc = 0.0f;
  const float* row = be2 + (size_t)i*64;
  const float* hr  = h + (size_t)n*64;
  for (int j = 0; j < 64; ++j)
    acc = fmaf(row[j], hr[j], acc);
  bh[idx] = acc;
}

// ---- CSR by src ----
__global__ void k_hist(const int* __restrict__ ei, int* __restrict__ deg){
  int e = blockIdx.x*256 + threadIdx.x;
  if (e >= N_EDGES) return;
  atomicAdd(&deg[ei[N_EDGES + e]], 1);
}

__global__ void k_scan(const int* __restrict__ deg, int* __restrict__ rowptr,
                       int* __restrict__ cursor){
  __shared__ int part[256];
  int t = threadIdx.x;
  int base = t*40;
  int s = 0;
  for (int i = 0; i < 40; ++i){
    int idx = base + i;
    if (idx < N_NODES) s += deg[idx];
  }
  part[t] = s;
  __syncthreads();
  for (int off = 1; off < 256; off <<= 1){
    int v = (t >= off) ? part[t - off] : 0;
    __syncthreads();
    part[t] += v;
    __syncthreads();
  }
  int run = (t > 0) ? part[t - 1] : 0;
  for (int i = 0; i < 40; ++i){
    int idx = base + i;
    if (idx < N_NODES){
      rowptr[idx] = run;
      cursor[idx] = run;
      run += deg[idx];
    }
  }
  if (t == 255) rowptr[N_NODES] = run;
}

__global__ void k_scatter(const int* __restrict__ ei, int* __restrict__ cursor,
                          int* __restrict__ csr){
  int e = blockIdx.x*256 + threadIdx.x;
  if (e >= N_EDGES) return;
  int src = ei[N_EDGES + e];
  int pos = atomicAdd(&cursor[src], 1);
  csr[pos] = e;
}

// ---- FUSED cgemm + message kernel (mfma path) ----
// Block (tm, q): computes C-quarter for 16 nodes [128 k][i in q*16..q*16+16)
// in LDS (never touches HBM), then runs the per-src-node message MFMAs for
// those nodes on this i-quarter and atomicAdds into m[dst][q*16+colb].
// Messages are additive over the i-split, so the 4 q-blocks are independent.
// LDS row padded (520 halves) so the 4-quad epilogue write aliases 2-way
// (free) while msg-phase reads stay lane-contiguous (conflict-free).
__global__ void MPNN_55705725829535_kernel(const half_t* __restrict__ AT,
                                           const half_t* __restrict__ BT,
                                           const int* __restrict__ rowptr,
                                           const int* __restrict__ csr,
                                           const int* __restrict__ ei,
                                           const half_t* __restrict__ Hid16,
                                           const float* __restrict__ bh,
                                           float* __restrict__ m){
  __shared__ half_t Ct[16][4][520];
  __shared__ int dstW[4][16];
  int wv   = threadIdx.x >> 6;
  int lane = threadIdx.x & 63;
  int quad = lane >> 4;
  int colb = lane & 15;
  int tm = blockIdx.x;           // 0..624
  int q  = blockIdx.y;           // 0..3 (i-quarter)

  // ---- phase 1: C-quarter GEMM into LDS ----
  const f16x8* Ab = (const f16x8*)AT + (size_t)tm*128;
  f16x8 a0 = Ab[lane];
  f16x8 a1 = Ab[64 + lane];
  #pragma unroll
  for (int kt = 0; kt < 4; ++kt){
    f32x4 acc[8];
    #pragma unroll
    for (int jj = 0; jj < 8; ++jj){
      acc[jj][0]=0.f; acc[jj][1]=0.f; acc[jj][2]=0.f; acc[jj][3]=0.f;
    }
    #pragma unroll
    for (int jj = 0; jj < 8; ++jj){
      int ke = kt*32 + wv*8 + jj;
      int tn = ke*4 + q;
      const f16x8* Bb = (const f16x8*)BT + (size_t)tn*128;
      acc[jj] = __builtin_amdgcn_mfma_f32_16x16x32_f16(a0, Bb[lane],      acc[jj], 0, 0, 0);
      acc[jj] = __builtin_amdgcn_mfma_f32_16x16x32_f16(a1, Bb[64 + lane], acc[jj], 0, 0, 0);
    }
    #pragma unroll
    for (int r = 0; r < 4; ++r){
      int node = quad*4 + r;
      f16x8 v;
      #pragma unroll
      for (int jj = 0; jj < 8; ++jj) v[jj] = (half_t)acc[jj][r];
      *(f16x8*)&Ct[node][kt][(wv*16 + colb)*8] = v;
    }
  }
  __syncthreads();

  // ---- phase 2: message MFMAs from LDS, 4 nodes per wave ----
  for (int c = 0; c < 4; ++c){
    int node = wv*4 + c;
    int s = tm*16 + node;        // 625*16 == 10000 exactly
    int beg  = rowptr[s];
    int endp = rowptr[s + 1];
    if (beg == endp) continue;
    f16x8 B[4];
    #pragma unroll
    for (int kt = 0; kt < 4; ++kt)
      B[kt] = *(const f16x8*)&Ct[node][kt][lane*8];
    float bhc = bh[(size_t)s*64 + q*16 + colb];
    for (int gbeg = beg; gbeg < endp; gbeg += 16){
      int gn = endp - gbeg; if (gn > 16) gn = 16;
      if (lane < 16)
        dstW[wv][lane] = (lane < gn) ? ei[csr[gbeg + lane]] : -1;
      f16x8 A[4];
      if (colb < gn){
        int e = csr[gbeg + colb];
        const f16x8* Hb = (const f16x8*)(Hid16 + (size_t)e*128) + quad;
        #pragma unroll
        for (int kt = 0; kt < 4; ++kt)
          A[kt] = Hb[kt*4];
      } else {
        #pragma unroll
        for (int kt = 0; kt < 4; ++kt)
          #pragma unroll
          for (int p = 0; p < 8; ++p) A[kt][p] = (half_t)0;
      }
      f32x4 acc;
      acc[0]=0.f; acc[1]=0.f; acc[2]=0.f; acc[3]=0.f;
      #pragma unroll
      for (int kt = 0; kt < 4; ++kt)
        acc = __builtin_amdgcn_mfma_f32_16x16x32_f16(A[kt], B[kt], acc, 0, 0, 0);
      #pragma unroll
      for (int r = 0; r < 4; ++r){
        int jrow = quad*4 + r;
        if (jrow < gn){
          int d = dstW[wv][jrow];
          atomicAdd(&m[(size_t)d*64 + q*16 + colb], acc[r] + bhc);
        }
      }
    }
  }
}

// scalar cgemm (fallback, chunked): 2 cols/thread, fp16 stores, OLD linear C layout
__global__ void k_cgemm(const float* __restrict__ h, const float* __restrict__ Mm,
                        half_t* __restrict__ C, int lo, int hi){
  __shared__ float hs[16][64];
  int n0 = lo + blockIdx.x*16;
  int o0 = blockIdx.y*256 + threadIdx.x;
  for (int idx = threadIdx.x; idx < 16*64; idx += 256){
    int nn = idx >> 6, j = idx & 63;
    int node = n0 + nn;
    hs[nn][j] = (node < hi) ? h[(size_t)node*64 + j] : 0.0f;
  }
  __syncthreads();
  float acc0[16], acc1[16];
  #pragma unroll
  for (int nn = 0; nn < 16; ++nn){ acc0[nn] = 0.0f; acc1[nn] = 0.0f; }
  for (int j4 = 0; j4 < 16; ++j4){
    const float* M0 = Mm + (size_t)(j4*4)*8192;
    float a0 = M0[o0],            b0 = M0[o0 + 4096];
    float a1 = M0[8192 + o0],     b1 = M0[8192 + o0 + 4096];
    float a2 = M0[2*8192 + o0],   b2 = M0[2*8192 + o0 + 4096];
    float a3 = M0[3*8192 + o0],   b3 = M0[3*8192 + o0 + 4096];
    #pragma unroll
    for (int nn = 0; nn < 16; ++nn){
      float4 hv = *(const float4*)&hs[nn][j4*4];
      acc0[nn] = fmaf(hv.x, a0, acc0[nn]);
      acc1[nn] = fmaf(hv.x, b0, acc1[nn]);
      acc0[nn] = fmaf(hv.y, a1, acc0[nn]);
      acc1[nn] = fmaf(hv.y, b1, acc1[nn]);
      acc0[nn] = fmaf(hv.z, a2, acc0[nn]);
      acc1[nn] = fmaf(hv.z, b2, acc1[nn]);
      acc0[nn] = fmaf(hv.w, a3, acc0[nn]);
      acc1[nn] = fmaf(hv.w, b3, acc1[nn]);
    }
  }
  #pragma unroll
  for (int nn = 0; nn < 16; ++nn){
    int node = n0 + nn;
    if (node < hi){
      half_t* Cr = C + (size_t)(node - lo)*8192;
      Cr[o0]        = (half_t)acc0[nn];
      Cr[o0 + 4096] = (half_t)acc1[nn];
    }
  }
}

// old-style streaming msg kernel (fallback path, fp32 Hid, OLD linear C layout)
__global__ void k_msg_csr(const int* __restrict__ rowptr,
                          const int* __restrict__ csr,
                          const int* __restrict__ ei,
                          const float* __restrict__ Hid,
                          const half_t* __restrict__ C,
                          const float* __restrict__ bh,
                          float* __restrict__ m, int lo, int hi){
  __shared__ float hidL[4][8][128];
  int wave = threadIdx.x >> 6;
  int lane = threadIdx.x & 63;
  int s = lo + blockIdx.x*4 + wave;
  if (s >= hi) return;
  int beg = rowptr[s];
  int endp = rowptr[s + 1];
  if (beg == endp) return;
  float bhv = bh[(size_t)s*64 + lane];
  const half_t* Cb = C + (size_t)(s - lo)*8192 + lane;
  float (*hl)[128] = hidL[wave];
  for (int gbeg = beg; gbeg < endp; gbeg += 8){
    int gn = endp - gbeg; if (gn > 8) gn = 8;
    int dsts[8];
    int e0 = csr[gbeg];
    #pragma unroll
    for (int j = 0; j < 8; ++j){
      int e = (j < gn) ? csr[gbeg + j] : e0;
      dsts[j] = ei[e];
      hl[j][lane]      = Hid[(size_t)e*128 + lane];
      hl[j][lane + 64] = Hid[(size_t)e*128 + 64 + lane];
    }
    float acc[8];
    #pragma unroll
    for (int j = 0; j < 8; ++j) acc[j] = 0.0f;
    #pragma unroll 4
    for (int k = 0; k < 128; ++k){
      float c = (float)Cb[k*64];
      #pragma unroll
      for (int j = 0; j < 8; ++j)
        acc[j] = fmaf(hl[j][k], c, acc[j]);
    }
    for (int j = 0; j < gn; ++j)
      atomicAdd(&m[(size_t)dsts[j]*64 + lane], acc[j] + bhv);
  }
}

// fallback per-edge bilinear (only if ws too small for the C path)
__global__ void k_msg_fb(const int* __restrict__ ei, const float* __restrict__ ef,
                         const float* __restrict__ W1, const float* __restrict__ b1,
                         const float* __restrict__ W2, const float* __restrict__ be2,
                         const float* __restrict__ h, float* __restrict__ m){
  __shared__ float HidL[EHID];
  __shared__ __align__(16) float hsL[HID];
  int e = blockIdx.x;
  int t = threadIdx.x;
  int src = ei[N_EDGES + e];
  int dst = ei[e];
  {
    float a0 = b1[t];
    float a1 = b1[t + 64];
    const float* er = ef + (size_t)e*EDGE_DIM;
    for (int j = 0; j < EDGE_DIM; ++j){
      float ev = er[j];
      a0 = fmaf(ev, W1[j*EHID + t],      a0);
      a1 = fmaf(ev, W1[j*EHID + t + 64], a1);
    }
    HidL[t]      = fmaxf(a0, 0.0f);
    HidL[t + 64] = fmaxf(a1, 0.0f);
    hsL[t] = h[(size_t)src*64 + t];
  }
  __syncthreads();
  float acc = 0.0f;
  for (int k = 0; k < EHID; ++k){
    float s = HidL[k];
    if (s != 0.0f){
      const float* w = W2 + (size_t)k*4096 + t*64;
      float partial = 0.0f;
      for (int j = 0; j < 64; ++j)
        partial = fmaf(hsL[j], w[j], partial);
      acc = fmaf(s, partial, acc);
    }
  }
  {
    const float* w = be2 + (size_t)t*64;
    for (int j = 0; j < 64; ++j)
      acc = fmaf(hsL[j], w[j], acc);
  }
  atomicAdd(&m[(size_t)dst*64 + t], acc);
}

// GRU: 256 threads = 4 waves, 16 nodes/block (4 per wave).
__global__ void k_gru(float* __restrict__ h, const float* __restrict__ m,
                      const float* __restrict__ WgT, const float* __restrict__ WhT,
                      const float* __restrict__ bg, const float* __restrict__ bhb){
  __shared__ float mld[16][64];
  __shared__ float hld[16][64];
  int t  = threadIdx.x;
  int i  = t & 63;
  int wv = t >> 6;                  // 0..3
  int n0 = blockIdx.x*16;           // 625*16 == 10000 exactly
  for (int idx = t; idx < 16*64; idx += 256){
    int nn = idx >> 6, j = idx & 63;
    int node = n0 + nn;
    mld[nn][j] = m[(size_t)node*64 + j];
    hld[nn][j] = h[(size_t)node*64 + j];
  }
  __syncthreads();
  float xr[4], xz[4], xn[4], hr[4], hz[4], hn[4];
  #pragma unroll
  for (int c = 0; c < 4; ++c){
    xr[c] = bg[i];  xz[c] = bg[64 + i];  xn[c] = bg[128 + i];
    hr[c] = bhb[i]; hz[c] = bhb[64 + i]; hn[c] = bhb[128 + i];
  }
  for (int j = 0; j < 64; ++j){
    const float* wg = WgT + j*192;
    const float* wh = WhT + j*192;
    float wgr = wg[i], wgz = wg[64 + i], wgn = wg[128 + i];
    float whr = wh[i], whz = wh[64 + i], whn = wh[128 + i];
    #pragma unroll
    for (int c = 0; c < 4; ++c){
      int nn = wv*4 + c;
      float mj = mld[nn][j];
      float hj = hld[nn][j];
      xr[c] = fmaf(mj, wgr, xr[c]);
      xz[c] = fmaf(mj, wgz, xz[c]);
      xn[c] = fmaf(mj, wgn, xn[c]);
      hr[c] = fmaf(hj, whr, hr[c]);
      hz[c] = fmaf(hj, whz, hz[c]);
      hn[c] = fmaf(hj, whn, hn[c]);
    }
  }
  #pragma unroll
  for (int c = 0; c < 4; ++c){
    int nn = wv*4 + c;
    float r  = sigf(xr[c] + hr[c]);
    float z  = sigf(xz[c] + hz[c]);
    float nv = tanhf(xn[c] + r*hn[c]);
    h[(size_t)(n0 + nn)*64 + i] = (1.0f - z)*nv + z*hld[nn][i];
  }
}

// Set2Set + LSTM + readout; 512 threads: rsb 8-way split, gates 2-way split.
// Direct Wli/Wlh reads (per-thread sequential rows vectorize to dwordx4 and
// L1-hit; r1's coalesced-WcT layout REGRESSED 56->95us — do not retry).
__global__ void k_s2s(const float* __restrict__ h,
                      const float* __restrict__ Wli, const float* __restrict__ Wlh,
                      const float* __restrict__ bli, const float* __restrict__ blh,
                      const float* __restrict__ Wm1, const float* __restrict__ bm1,
                      const float* __restrict__ Wm2, const float* __restrict__ bm2,
                      float* __restrict__ out){
  __shared__ float hc[157*65];
  __shared__ float ea[160];
  __shared__ float x[192];
  __shared__ float gpart[512];
  __shared__ float rsp[8][64];
  __shared__ float wredA[8];
  __shared__ float wredB[8];
  __shared__ float hsb[64];
  __shared__ float csb[64];
  __shared__ float rsb[64];
  int g = blockIdx.x;
  int t = threadIdx.x;          // 0..511
  int lane = t & 63;
  int wv   = t >> 6;            // 0..7
  int start = (g*N_NODES + 63) >> 6;
  int end   = ((g + 1)*N_NODES + 63) >> 6;
  int cnt = end - start;        // 156 or 157
  const float* hg = h + (size_t)start*64;
  for (int idx = t; idx < cnt*64; idx += 512)
    hc[(idx >> 6)*65 + (idx & 63)] = hg[idx];
  if (t < 64){ hsb[t] = 0.0f; csb[t] = 0.0f; rsb[t] = 0.0f; }
  __syncthreads();
  for (int step = 0; step < S2S_STEPS; ++step){
    float ev = -1e30f;
    if (t < cnt){
      float a = 0.0f;
      const float* hr = &hc[t*65];
      for (int i = 0; i < 64; ++i) a = fmaf(hr[i], hsb[i], a);
      ev = a;
    }
    float v = ev;
    for (int o = 32; o > 0; o >>= 1) v = fmaxf(v, __shfl_xor(v, o));
    if (lane == 0) wredA[wv] = v;
    __syncthreads();                                      // S1
    float mx = wredA[0];
    #pragma unroll
    for (int i = 1; i < 8; ++i) mx = fmaxf(mx, wredA[i]);
    float ex = (t < cnt) ? expf(ev - mx) : 0.0f;
    float sv = ex;
    for (int o = 32; o > 0; o >>= 1) sv += __shfl_xor(sv, o);
    if (lane == 0) wredB[wv] = sv;
    __syncthreads();                                      // S2
    float ssum = 0.0f;
    #pragma unroll
    for (int i = 0; i < 8; ++i) ssum += wredB[i];
    if (t < cnt) ea[t] = ex / (ssum + 1e-16f);
    __syncthreads();                                      // S3
    {
      int n0 = wv*20;
      int n1 = n0 + 20; if (n1 > cnt) n1 = cnt;
      float r = 0.0f;
      for (int n = n0; n < n1; ++n)
        r = fmaf(ea[n], hc[n*65 + lane], r);
      rsp[wv][lane] = r;
    }
    __syncthreads();                                      // S4
    if (t < 64){
      float r = rsp[0][t] + rsp[1][t] + rsp[2][t] + rsp[3][t]
              + rsp[4][t] + rsp[5][t] + rsp[6][t] + rsp[7][t];
      rsb[t] = r;
      x[t]        = hsb[t];
      x[64 + t]   = r;
      x[128 + t]  = hsb[t];
    }
    __syncthreads();                                      // S5
    {
      int gate = t & 255;
      int half = t >> 8;
      float gl = 0.0f;
      if (half == 0){
        const float* wr = Wli + (size_t)gate*128;
        for (int jj = 0; jj < 96; ++jj) gl = fmaf(x[jj], wr[jj], gl);
      } else {
        const float* wr = Wli + (size_t)gate*128;
        for (int jj = 96; jj < 128; ++jj) gl = fmaf(x[jj], wr[jj], gl);
        const float* wh = Wlh + (size_t)gate*64;
        for (int jj = 0; jj < 64; ++jj) gl = fmaf(x[128 + jj], wh[jj], gl);
      }
      gpart[t] = gl;
    }
    __syncthreads();                                      // S6
    if (t < 64){
      float iv = sigf (gpart[t]       + gpart[t + 256]       + bli[t]       + blh[t]);
      float fv = sigf (gpart[64 + t]  + gpart[64 + t + 256]  + bli[64 + t]  + blh[64 + t]);
      float gv = tanhf(gpart[128 + t] + gpart[128 + t + 256] + bli[128 + t] + blh[128 + t]);
      float ov = sigf (gpart[192 + t] + gpart[192 + t + 256] + bli[192 + t] + blh[192 + t]);
      float c  = fv*csb[t] + iv*gv;
      csb[t] = c;
      hsb[t] = ov*tanhf(c);
    }
    __syncthreads();                                      // S7
  }
  float rv = 0.0f;
  if (t < 64){
    float v = bm1[t];
    for (int j = 0; j < 64; ++j) v = fmaf(hsb[j], Wm1[(size_t)j*64 + t],        v);
    for (int j = 0; j < 64; ++j) v = fmaf(rsb[j], Wm1[(size_t)(64 + j)*64 + t], v);
    v = fmaxf(v, 0.0f);
    rv = v * Wm2[t];
  }
  for (int o = 32; o > 0; o >>= 1) rv += __shfl_xor(rv, o);
  if (lane == 0) wredA[wv] = rv;
  __syncthreads();
  if (t == 0) out[g] = wredA[0] + wredA[1] + wredA[2] + wredA[3]
                     + wredA[4] + wredA[5] + wredA[6] + wredA[7] + bm2[0];
}

extern "C" void kernel_launch(void* const* d_in, const int* in_sizes, int n_in,
                              void* d_out, int out_size, void* d_ws, size_t ws_size,
                              hipStream_t stream){
  (void)in_sizes; (void)n_in; (void)out_size;

  const float* nf  = (const float*)d_in[0];
  const float* ef  = (const float*)d_in[1];
  const int*   ei  = (const int*)d_in[2];
  const float* Wp  = (const float*)d_in[4];
  const float* bp  = (const float*)d_in[5];
  const float* We1 = (const float*)d_in[6];
  const float* be1 = (const float*)d_in[7];
  const float* We2 = (const float*)d_in[8];
  const float* be2 = (const float*)d_in[9];
  const float* Wg  = (const float*)d_in[10];
  const float* Wh  = (const float*)d_in[11];
  const float* bg  = (const float*)d_in[12];
  const float* bhb = (const float*)d_in[13];
  const float* Wli = (const float*)d_in[14];
  const float* Wlh = (const float*)d_in[15];
  const float* bli = (const float*)d_in[16];
  const float* blh = (const float*)d_in[17];
  const float* Wm1 = (const float*)d_in[18];
  const float* bm1 = (const float*)d_in[19];
  const float* Wm2 = (const float*)d_in[20];
  const float* bm2 = (const float*)d_in[21];

  float* out = (float*)d_out;
  float* ws  = (float*)d_ws;

  float* h    = ws;                         //   640000
  float* m    = ws + 640000;                //   640000
  float* bh   = ws + 1280000;               //   640000
  float* Mm   = ws + 1920000;               //   524288  (fallback)
  float* WgT  = ws + 2444288;               //    12288
  float* WhT  = ws + 2456576;               //    12288
  float* Hid  = ws + 2468864;               //  6400000 (fp32 fallback / fp16 main)
  half_t* Hid16 = (half_t*)Hid;
  int*   deg    = (int*)(ws + 8868864);
  int*   rowptr = deg + 10000;
  int*   cursor = rowptr + 10001;
  int*   csr    = cursor + 10000;
  half_t* AT  = (half_t*)(ws + 8948880);
  half_t* BT  = (half_t*)(ws + 9268880);
  const size_t C_OFF = 9531024;             // floats
  half_t* C   = (half_t*)(ws + C_OFF);

  long long c_halves = ((long long)ws_size - (long long)C_OFF*4) / 2;
  int NC = (c_halves > 0) ? (int)(c_halves / 8192) : 0;
  if (NC > N_NODES) NC = N_NODES;
  int use_c_path = (NC >= 512);
  int use_mfma   = (NC >= N_NODES);   // mfma path no longer needs C, but keep
                                      // the proven ws-size gate

  k_proj<<<(N_NODES*HID + 255)/256, 256, 0, stream>>>(nf, Wp, bp, h);

  if (use_c_path){
    k_twg <<<(192*64 + 255)/256, 256, 0, stream>>>(Wg, Wh, WgT, WhT);
    k_zero<<<(10000 + 255)/256, 256, 0, stream>>>((float*)deg, 10000);
    k_hist<<<(N_EDGES + 255)/256, 256, 0, stream>>>(ei, deg);
    k_scan<<<1, 256, 0, stream>>>(deg, rowptr, cursor);
    k_scatter<<<(N_EDGES + 255)/256, 256, 0, stream>>>(ei, cursor, csr);
    if (use_mfma){
      k_ehid16<<<(N_EDGES*EHID + 255)/256, 256, 0, stream>>>(ef, We1, be1, Hid16);
      k_w2bt<<<(512*2*64*8 + 255)/256, 256, 0, stream>>>(We2, BT);
      for (int step = 0; step < T_STEPS; ++step){
        k_zero<<<(N_NODES*HID + 255)/256, 256, 0, stream>>>(m, N_NODES*HID);
        k_bh<<<(N_NODES*HID + 255)/256, 256, 0, stream>>>(h, be2, bh);
        k_h2a<<<(625*2*64*8 + 255)/256, 256, 0, stream>>>(h, AT);
        dim3 grid(625, 4);
        MPNN_55705725829535_kernel<<<grid, 256, 0, stream>>>(
            AT, BT, rowptr, csr, ei, Hid16, bh, m);
        k_gru<<<625, 256, 0, stream>>>(h, m, WgT, WhT, bg, bhb);
      }
    } else {
      k_ehid<<<(N_EDGES*EHID + 255)/256, 256, 0, stream>>>(ef, We1, be1, Hid);
      k_tw2<<<(64*8192)/256, 256, 0, stream>>>(We2, Mm);
      for (int step = 0; step < T_STEPS; ++step){
        k_zero<<<(N_NODES*HID + 255)/256, 256, 0, stream>>>(m, N_NODES*HID);
        k_bh<<<(N_NODES*HID + 255)/256, 256, 0, stream>>>(h, be2, bh);
        for (int lo = 0; lo < N_NODES; lo += NC){
          int hi = (lo + NC < N_NODES) ? lo + NC : N_NODES;
          int cnt = hi - lo;
          dim3 grid((cnt + 15)/16, 16);
          k_cgemm<<<grid, 256, 0, stream>>>(h, Mm, C, lo, hi);
          k_msg_csr<<<(cnt + 3)/4, 256, 0, stream>>>(
              rowptr, csr, ei, Hid, C, bh, m, lo, hi);
        }
        k_gru<<<625, 256, 0, stream>>>(h, m, WgT, WhT, bg, bhb);
      }
    }
  } else {
    k_twg <<<(192*64 + 255)/256, 256, 0, stream>>>(Wg, Wh, WgT, WhT);
    for (int step = 0; step < T_STEPS; ++step){
      k_zero<<<(N_NODES*HID + 255)/256, 256, 0, stream>>>(m, N_NODES*HID);
      k_msg_fb<<<N_EDGES, 64, 0, stream>>>(ei, ef, We1, be1, We2, be2, h, m);
      k_gru<<<625, 256, 0, stream>>>(h, m, WgT, WhT, bg, bhb);
    }
  }
  k_s2s<<<N_GRAPHS, 512, 0, stream>>>(h, Wli, Wlh, bli, blh,
                                      Wm1, bm1, Wm2, bm2, out);
}

// Round 5
// 582.649 us; speedup vs baseline: 1.2773x; 1.0318x over previous
//
#include <hip/hip_runtime.h>

#define N_NODES   10000
#define N_EDGES   50000
#define N_GRAPHS  64
#define NODE_DIM  32
#define EDGE_DIM  16
#define HID       64
#define EHID      128
#define T_STEPS   3
#define S2S_STEPS 6

typedef _Float16 half_t;
typedef _Float16 f16x8 __attribute__((ext_vector_type(8)));
typedef float    f32x4 __attribute__((ext_vector_type(4)));

__device__ __forceinline__ float sigf(float x){ return 1.0f/(1.0f + expf(-x)); }

__global__ void k_zero(float* p, int n){
  int i = blockIdx.x*256 + threadIdx.x;
  if (i < n) p[i] = 0.0f;
}

// h = nf @ W_proj + b_proj   (N x 64)
__global__ void k_proj(const float* __restrict__ nf, const float* __restrict__ Wp,
                       const float* __restrict__ bp, float* __restrict__ h){
  int idx = blockIdx.x*256 + threadIdx.x;
  if (idx >= N_NODES*HID) return;
  int n = idx >> 6;
  int c = idx & 63;
  float acc = bp[c];
  const float* row = nf + (size_t)n*NODE_DIM;
  for (int j = 0; j < NODE_DIM; ++j)
    acc = fmaf(row[j], Wp[j*HID + c], acc);
  h[idx] = acc;
}

// Mm (fp32, fallback path)
__global__ void k_tw2(const float* __restrict__ W2, float* __restrict__ Mm){
  int idx = blockIdx.x*256 + threadIdx.x;
  if (idx >= 64*8192) return;
  int j = idx >> 13; int o = idx & 8191; int k = o >> 6; int i = o & 63;
  Mm[idx] = W2[(size_t)k*4096 + i*64 + j];
}

// BT: W2 in MFMA B-fragment order (fp16), built once.
// BT[tn][tk][lane][j] : contraction k = tk*32 + (lane>>4)*8 + j (h-feature),
// output col o = tn*16 + (lane&15), o = k_edge*64 + i.
__global__ void k_w2bt(const float* __restrict__ W2, half_t* __restrict__ BT){
  int idx = blockIdx.x*256 + threadIdx.x;
  if (idx >= 512*2*64*8) return;
  int j    = idx & 7;
  int lane = (idx >> 3) & 63;
  int tk   = (idx >> 9) & 1;
  int tn   = idx >> 10;
  int k = tk*32 + ((lane >> 4) << 3) + j;
  int o = tn*16 + (lane & 15);
  BT[idx] = (half_t)W2[(size_t)(o >> 6)*4096 + (o & 63)*64 + k];
}

// AT: h in MFMA A-fragment order (fp16), per step (standalone, kept for clarity).
__global__ void k_h2a(const float* __restrict__ h, half_t* __restrict__ AT){
  int idx = blockIdx.x*256 + threadIdx.x;
  if (idx >= 625*2*64*8) return;
  int j    = idx & 7;
  int lane = (idx >> 3) & 63;
  int tk   = (idx >> 9) & 1;
  int tm   = idx >> 10;
  int mrow = tm*16 + (lane & 15);
  int k    = tk*32 + ((lane >> 4) << 3) + j;
  AT[idx] = (half_t)h[(size_t)mrow*64 + k];
}

// Fused per-step prep: m=0, bh = be2-rowdot(h), AT = h in A-fragment order.
// One dispatch instead of three over the same N*64 domain.
__global__ void k_prep(const float* __restrict__ h, const float* __restrict__ be2,
                       float* __restrict__ m, float* __restrict__ bhp,
                       half_t* __restrict__ AT){
  int idx = blockIdx.x*256 + threadIdx.x;
  if (idx >= N_NODES*HID) return;
  m[idx] = 0.0f;
  int n = idx >> 6, i = idx & 63;
  float acc = 0.0f;
  const float* row = be2 + (size_t)i*64;
  const float* hr  = h + (size_t)n*64;
  for (int j = 0; j < 64; ++j)
    acc = fmaf(row[j], hr[j], acc);
  bhp[idx] = acc;
  int j    = idx & 7;
  int lane = (idx >> 3) & 63;
  int tk   = (idx >> 9) & 1;
  int tm   = idx >> 10;
  int mrow = tm*16 + (lane & 15);
  int k    = tk*32 + ((lane >> 4) << 3) + j;
  AT[idx] = (half_t)h[(size_t)mrow*64 + k];
}

// GRU weight transposes
__global__ void k_twg(const float* __restrict__ Wg, const float* __restrict__ Wh,
                      float* __restrict__ WgT, float* __restrict__ WhT){
  int idx = blockIdx.x*256 + threadIdx.x;
  if (idx >= 192*64) return;
  int row = idx >> 6;
  int j   = idx & 63;
  WgT[j*192 + row] = Wg[(size_t)row*64 + j];
  WhT[j*192 + row] = Wh[(size_t)row*64 + j];
}

// Hid = relu(ef @ W_e1 + b_e1)  fp32 (fallback path)
__global__ void k_ehid(const float* __restrict__ ef, const float* __restrict__ W1,
                       const float* __restrict__ b1, float* __restrict__ Hid){
  int idx = blockIdx.x*256 + threadIdx.x;
  if (idx >= N_EDGES*EHID) return;
  int e = idx >> 7, c = idx & 127;
  float acc = b1[c];
  const float* er = ef + (size_t)e*EDGE_DIM;
  for (int j = 0; j < EDGE_DIM; ++j)
    acc = fmaf(er[j], W1[j*EHID + c], acc);
  Hid[idx] = fmaxf(acc, 0.0f);
}

// Hid16 = relu(ef @ W_e1 + b_e1) in fp16 (MFMA message path)
__global__ void k_ehid16(const float* __restrict__ ef, const float* __restrict__ W1,
                         const float* __restrict__ b1, half_t* __restrict__ Hid16){
  int idx = blockIdx.x*256 + threadIdx.x;
  if (idx >= N_EDGES*EHID) return;
  int e = idx >> 7, c = idx & 127;
  float acc = b1[c];
  const float* er = ef + (size_t)e*EDGE_DIM;
  for (int j = 0; j < EDGE_DIM; ++j)
    acc = fmaf(er[j], W1[j*EHID + c], acc);
  Hid16[idx] = (half_t)fmaxf(acc, 0.0f);
}

// bh[n,i] = sum_j be2[i*64+j] * h[n,j]  (fallback path)
__global__ void k_bh(const float* __restrict__ h, const float* __restrict__ be2,
                     float* __restrict__ bh){
  int idx = blockIdx.x*256 + threadIdx.x;
  if (idx >= N_NODES*HID) return;
  int n = idx >> 6, i = idx & 63;
  float acc = 0.0f;
  const float* row = be2 + (size_t)i*64;
  const float* hr  = h + (size_t)n*64;
  for (int j = 0; j < 64; ++j)
    acc = fmaf(row[j], hr[j], acc);
  bh[idx] = acc;
}

// ---- CSR by src ----
__global__ void k_hist(const int* __restrict__ ei, int* __restrict__ deg){
  int e = blockIdx.x*256 + threadIdx.x;
  if (e >= N_EDGES) return;
  atomicAdd(&deg[ei[N_EDGES + e]], 1);
}

__global__ void k_scan(const int* __restrict__ deg, int* __restrict__ rowptr,
                       int* __restrict__ cursor){
  __shared__ int part[256];
  int t = threadIdx.x;
  int base = t*40;
  int s = 0;
  for (int i = 0; i < 40; ++i){
    int idx = base + i;
    if (idx < N_NODES) s += deg[idx];
  }
  part[t] = s;
  __syncthreads();
  for (int off = 1; off < 256; off <<= 1){
    int v = (t >= off) ? part[t - off] : 0;
    __syncthreads();
    part[t] += v;
    __syncthreads();
  }
  int run = (t > 0) ? part[t - 1] : 0;
  for (int i = 0; i < 40; ++i){
    int idx = base + i;
    if (idx < N_NODES){
      rowptr[idx] = run;
      cursor[idx] = run;
      run += deg[idx];
    }
  }
  if (t == 255) rowptr[N_NODES] = run;
}

__global__ void k_scatter(const int* __restrict__ ei, int* __restrict__ cursor,
                          int* __restrict__ csr){
  int e = blockIdx.x*256 + threadIdx.x;
  if (e >= N_EDGES) return;
  int src = ei[N_EDGES + e];
  int pos = atomicAdd(&cursor[src], 1);
  csr[pos] = e;
}

// ---- FUSED cgemm + message kernel (mfma path) ----
// r5: 8 nodes/block (was 16) -> LDS 33KB -> 4 blocks/CU (occupancy 19.6%->~40%)
// to attack the latency-bound profile (r4: MfmaUtil 6%, VALU 11%, HBM 8%).
// A-fragment rows 8..15 duplicate rows 0..7 (results discarded) — MFMA was 6%
// util, doubling it is ~free; occupancy is the binding constraint.
// Block (tmb, q): C-quarter for 8 nodes [128 k][i in q*16..) in LDS, then
// per-src-node message MFMAs, atomicAdd into m[dst][q*16+colb].
__global__ void MPNN_55705725829535_kernel(const half_t* __restrict__ AT,
                                           const half_t* __restrict__ BT,
                                           const int* __restrict__ rowptr,
                                           const int* __restrict__ csr,
                                           const int* __restrict__ ei,
                                           const half_t* __restrict__ Hid16,
                                           const float* __restrict__ bh,
                                           float* __restrict__ m){
  __shared__ half_t Ct[8][4][520];
  __shared__ int dstW[4][16];
  int wv   = threadIdx.x >> 6;
  int lane = threadIdx.x & 63;
  int quad = lane >> 4;
  int colb = lane & 15;
  int tmb = blockIdx.x;          // 0..1249 (8-node tile)
  int q   = blockIdx.y;          // 0..3 (i-quarter)
  int tile = tmb >> 1;           // 16-node AT tile
  int hi   = tmb & 1;            // which half of the tile

  // ---- phase 1: C-quarter GEMM into LDS ----
  // rows 0..7 = our nodes; lanes with (lane&15)>=8 duplicate rows 0..7.
  int srcl = (lane & 48) | (hi << 3) | (lane & 7);
  const f16x8* Ab = (const f16x8*)AT + (size_t)tile*128;
  f16x8 a0 = Ab[srcl];
  f16x8 a1 = Ab[64 + srcl];
  #pragma unroll
  for (int kt = 0; kt < 4; ++kt){
    f32x4 acc[8];
    #pragma unroll
    for (int jj = 0; jj < 8; ++jj){
      acc[jj][0]=0.f; acc[jj][1]=0.f; acc[jj][2]=0.f; acc[jj][3]=0.f;
    }
    #pragma unroll
    for (int jj = 0; jj < 8; ++jj){
      int ke = kt*32 + wv*8 + jj;
      int tn = ke*4 + q;
      const f16x8* Bb = (const f16x8*)BT + (size_t)tn*128;
      acc[jj] = __builtin_amdgcn_mfma_f32_16x16x32_f16(a0, Bb[lane],      acc[jj], 0, 0, 0);
      acc[jj] = __builtin_amdgcn_mfma_f32_16x16x32_f16(a1, Bb[64 + lane], acc[jj], 0, 0, 0);
    }
    if (quad < 2){
      #pragma unroll
      for (int r = 0; r < 4; ++r){
        int node = quad*4 + r;       // 0..7
        f16x8 v;
        #pragma unroll
        for (int jj = 0; jj < 8; ++jj) v[jj] = (half_t)acc[jj][r];
        *(f16x8*)&Ct[node][kt][(wv*16 + colb)*8] = v;
      }
    }
  }
  __syncthreads();

  // ---- phase 2: message MFMAs from LDS, 2 nodes per wave ----
  for (int c = 0; c < 2; ++c){
    int node = wv*2 + c;           // 0..7
    int s = tmb*8 + node;          // 1250*8 == 10000 exactly
    int beg  = rowptr[s];
    int endp = rowptr[s + 1];
    if (beg == endp) continue;
    f16x8 B[4];
    #pragma unroll
    for (int kt = 0; kt < 4; ++kt)
      B[kt] = *(const f16x8*)&Ct[node][kt][lane*8];
    float bhc = bh[(size_t)s*64 + q*16 + colb];
    for (int gbeg = beg; gbeg < endp; gbeg += 16){
      int gn = endp - gbeg; if (gn > 16) gn = 16;
      if (lane < 16)
        dstW[wv][lane] = (lane < gn) ? ei[csr[gbeg + lane]] : -1;
      f16x8 A[4];
      if (colb < gn){
        int e = csr[gbeg + colb];
        const f16x8* Hb = (const f16x8*)(Hid16 + (size_t)e*128) + quad;
        #pragma unroll
        for (int kt = 0; kt < 4; ++kt)
          A[kt] = Hb[kt*4];
      } else {
        #pragma unroll
        for (int kt = 0; kt < 4; ++kt)
          #pragma unroll
          for (int p = 0; p < 8; ++p) A[kt][p] = (half_t)0;
      }
      f32x4 acc;
      acc[0]=0.f; acc[1]=0.f; acc[2]=0.f; acc[3]=0.f;
      #pragma unroll
      for (int kt = 0; kt < 4; ++kt)
        acc = __builtin_amdgcn_mfma_f32_16x16x32_f16(A[kt], B[kt], acc, 0, 0, 0);
      #pragma unroll
      for (int r = 0; r < 4; ++r){
        int jrow = quad*4 + r;
        if (jrow < gn){
          int d = dstW[wv][jrow];
          atomicAdd(&m[(size_t)d*64 + q*16 + colb], acc[r] + bhc);
        }
      }
    }
  }
}

// scalar cgemm (fallback, chunked): 2 cols/thread, fp16 stores, OLD linear C layout
__global__ void k_cgemm(const float* __restrict__ h, const float* __restrict__ Mm,
                        half_t* __restrict__ C, int lo, int hi){
  __shared__ float hs[16][64];
  int n0 = lo + blockIdx.x*16;
  int o0 = blockIdx.y*256 + threadIdx.x;
  for (int idx = threadIdx.x; idx < 16*64; idx += 256){
    int nn = idx >> 6, j = idx & 63;
    int node = n0 + nn;
    hs[nn][j] = (node < hi) ? h[(size_t)node*64 + j] : 0.0f;
  }
  __syncthreads();
  float acc0[16], acc1[16];
  #pragma unroll
  for (int nn = 0; nn < 16; ++nn){ acc0[nn] = 0.0f; acc1[nn] = 0.0f; }
  for (int j4 = 0; j4 < 16; ++j4){
    const float* M0 = Mm + (size_t)(j4*4)*8192;
    float a0 = M0[o0],            b0 = M0[o0 + 4096];
    float a1 = M0[8192 + o0],     b1 = M0[8192 + o0 + 4096];
    float a2 = M0[2*8192 + o0],   b2 = M0[2*8192 + o0 + 4096];
    float a3 = M0[3*8192 + o0],   b3 = M0[3*8192 + o0 + 4096];
    #pragma unroll
    for (int nn = 0; nn < 16; ++nn){
      float4 hv = *(const float4*)&hs[nn][j4*4];
      acc0[nn] = fmaf(hv.x, a0, acc0[nn]);
      acc1[nn] = fmaf(hv.x, b0, acc1[nn]);
      acc0[nn] = fmaf(hv.y, a1, acc0[nn]);
      acc1[nn] = fmaf(hv.y, b1, acc1[nn]);
      acc0[nn] = fmaf(hv.z, a2, acc0[nn]);
      acc1[nn] = fmaf(hv.z, b2, acc1[nn]);
      acc0[nn] = fmaf(hv.w, a3, acc0[nn]);
      acc1[nn] = fmaf(hv.w, b3, acc1[nn]);
    }
  }
  #pragma unroll
  for (int nn = 0; nn < 16; ++nn){
    int node = n0 + nn;
    if (node < hi){
      half_t* Cr = C + (size_t)(node - lo)*8192;
      Cr[o0]        = (half_t)acc0[nn];
      Cr[o0 + 4096] = (half_t)acc1[nn];
    }
  }
}

// old-style streaming msg kernel (fallback path, fp32 Hid, OLD linear C layout)
__global__ void k_msg_csr(const int* __restrict__ rowptr,
                          const int* __restrict__ csr,
                          const int* __restrict__ ei,
                          const float* __restrict__ Hid,
                          const half_t* __restrict__ C,
                          const float* __restrict__ bh,
                          float* __restrict__ m, int lo, int hi){
  __shared__ float hidL[4][8][128];
  int wave = threadIdx.x >> 6;
  int lane = threadIdx.x & 63;
  int s = lo + blockIdx.x*4 + wave;
  if (s >= hi) return;
  int beg = rowptr[s];
  int endp = rowptr[s + 1];
  if (beg == endp) return;
  float bhv = bh[(size_t)s*64 + lane];
  const half_t* Cb = C + (size_t)(s - lo)*8192 + lane;
  float (*hl)[128] = hidL[wave];
  for (int gbeg = beg; gbeg < endp; gbeg += 8){
    int gn = endp - gbeg; if (gn > 8) gn = 8;
    int dsts[8];
    int e0 = csr[gbeg];
    #pragma unroll
    for (int j = 0; j < 8; ++j){
      int e = (j < gn) ? csr[gbeg + j] : e0;
      dsts[j] = ei[e];
      hl[j][lane]      = Hid[(size_t)e*128 + lane];
      hl[j][lane + 64] = Hid[(size_t)e*128 + 64 + lane];
    }
    float acc[8];
    #pragma unroll
    for (int j = 0; j < 8; ++j) acc[j] = 0.0f;
    #pragma unroll 4
    for (int k = 0; k < 128; ++k){
      float c = (float)Cb[k*64];
      #pragma unroll
      for (int j = 0; j < 8; ++j)
        acc[j] = fmaf(hl[j][k], c, acc[j]);
    }
    for (int j = 0; j < gn; ++j)
      atomicAdd(&m[(size_t)dsts[j]*64 + lane], acc[j] + bhv);
  }
}

// fallback per-edge bilinear (only if ws too small for the C path)
__global__ void k_msg_fb(const int* __restrict__ ei, const float* __restrict__ ef,
                         const float* __restrict__ W1, const float* __restrict__ b1,
                         const float* __restrict__ W2, const float* __restrict__ be2,
                         const float* __restrict__ h, float* __restrict__ m){
  __shared__ float HidL[EHID];
  __shared__ __align__(16) float hsL[HID];
  int e = blockIdx.x;
  int t = threadIdx.x;
  int src = ei[N_EDGES + e];
  int dst = ei[e];
  {
    float a0 = b1[t];
    float a1 = b1[t + 64];
    const float* er = ef + (size_t)e*EDGE_DIM;
    for (int j = 0; j < EDGE_DIM; ++j){
      float ev = er[j];
      a0 = fmaf(ev, W1[j*EHID + t],      a0);
      a1 = fmaf(ev, W1[j*EHID + t + 64], a1);
    }
    HidL[t]      = fmaxf(a0, 0.0f);
    HidL[t + 64] = fmaxf(a1, 0.0f);
    hsL[t] = h[(size_t)src*64 + t];
  }
  __syncthreads();
  float acc = 0.0f;
  for (int k = 0; k < EHID; ++k){
    float s = HidL[k];
    if (s != 0.0f){
      const float* w = W2 + (size_t)k*4096 + t*64;
      float partial = 0.0f;
      for (int j = 0; j < 64; ++j)
        partial = fmaf(hsL[j], w[j], partial);
      acc = fmaf(s, partial, acc);
    }
  }
  {
    const float* w = be2 + (size_t)t*64;
    for (int j = 0; j < 64; ++j)
      acc = fmaf(hsL[j], w[j], acc);
  }
  atomicAdd(&m[(size_t)dst*64 + t], acc);
}

// GRU: 256 threads = 4 waves, 16 nodes/block (4 per wave).
__global__ void k_gru(float* __restrict__ h, const float* __restrict__ m,
                      const float* __restrict__ WgT, const float* __restrict__ WhT,
                      const float* __restrict__ bg, const float* __restrict__ bhb){
  __shared__ float mld[16][64];
  __shared__ float hld[16][64];
  int t  = threadIdx.x;
  int i  = t & 63;
  int wv = t >> 6;                  // 0..3
  int n0 = blockIdx.x*16;           // 625*16 == 10000 exactly
  for (int idx = t; idx < 16*64; idx += 256){
    int nn = idx >> 6, j = idx & 63;
    int node = n0 + nn;
    mld[nn][j] = m[(size_t)node*64 + j];
    hld[nn][j] = h[(size_t)node*64 + j];
  }
  __syncthreads();
  float xr[4], xz[4], xn[4], hr[4], hz[4], hn[4];
  #pragma unroll
  for (int c = 0; c < 4; ++c){
    xr[c] = bg[i];  xz[c] = bg[64 + i];  xn[c] = bg[128 + i];
    hr[c] = bhb[i]; hz[c] = bhb[64 + i]; hn[c] = bhb[128 + i];
  }
  for (int j = 0; j < 64; ++j){
    const float* wg = WgT + j*192;
    const float* wh = WhT + j*192;
    float wgr = wg[i], wgz = wg[64 + i], wgn = wg[128 + i];
    float whr = wh[i], whz = wh[64 + i], whn = wh[128 + i];
    #pragma unroll
    for (int c = 0; c < 4; ++c){
      int nn = wv*4 + c;
      float mj = mld[nn][j];
      float hj = hld[nn][j];
      xr[c] = fmaf(mj, wgr, xr[c]);
      xz[c] = fmaf(mj, wgz, xz[c]);
      xn[c] = fmaf(mj, wgn, xn[c]);
      hr[c] = fmaf(hj, whr, hr[c]);
      hz[c] = fmaf(hj, whz, hz[c]);
      hn[c] = fmaf(hj, whn, hn[c]);
    }
  }
  #pragma unroll
  for (int c = 0; c < 4; ++c){
    int nn = wv*4 + c;
    float r  = sigf(xr[c] + hr[c]);
    float z  = sigf(xz[c] + hz[c]);
    float nv = tanhf(xn[c] + r*hn[c]);
    h[(size_t)(n0 + nn)*64 + i] = (1.0f - z)*nv + z*hld[nn][i];
  }
}

// Set2Set + LSTM + readout; 512 threads: rsb 8-way split, gates 2-way split.
// Direct Wli/Wlh reads (per-thread sequential rows vectorize to dwordx4 and
// L1-hit; r1's coalesced-WcT layout REGRESSED 56->95us — do not retry).
__global__ void k_s2s(const float* __restrict__ h,
                      const float* __restrict__ Wli, const float* __restrict__ Wlh,
                      const float* __restrict__ bli, const float* __restrict__ blh,
                      const float* __restrict__ Wm1, const float* __restrict__ bm1,
                      const float* __restrict__ Wm2, const float* __restrict__ bm2,
                      float* __restrict__ out){
  __shared__ float hc[157*65];
  __shared__ float ea[160];
  __shared__ float x[192];
  __shared__ float gpart[512];
  __shared__ float rsp[8][64];
  __shared__ float wredA[8];
  __shared__ float wredB[8];
  __shared__ float hsb[64];
  __shared__ float csb[64];
  __shared__ float rsb[64];
  int g = blockIdx.x;
  int t = threadIdx.x;          // 0..511
  int lane = t & 63;
  int wv   = t >> 6;            // 0..7
  int start = (g*N_NODES + 63) >> 6;
  int end   = ((g + 1)*N_NODES + 63) >> 6;
  int cnt = end - start;        // 156 or 157
  const float* hg = h + (size_t)start*64;
  for (int idx = t; idx < cnt*64; idx += 512)
    hc[(idx >> 6)*65 + (idx & 63)] = hg[idx];
  if (t < 64){ hsb[t] = 0.0f; csb[t] = 0.0f; rsb[t] = 0.0f; }
  __syncthreads();
  for (int step = 0; step < S2S_STEPS; ++step){
    float ev = -1e30f;
    if (t < cnt){
      float a = 0.0f;
      const float* hr = &hc[t*65];
      for (int i = 0; i < 64; ++i) a = fmaf(hr[i], hsb[i], a);
      ev = a;
    }
    float v = ev;
    for (int o = 32; o > 0; o >>= 1) v = fmaxf(v, __shfl_xor(v, o));
    if (lane == 0) wredA[wv] = v;
    __syncthreads();                                      // S1
    float mx = wredA[0];
    #pragma unroll
    for (int i = 1; i < 8; ++i) mx = fmaxf(mx, wredA[i]);
    float ex = (t < cnt) ? expf(ev - mx) : 0.0f;
    float sv = ex;
    for (int o = 32; o > 0; o >>= 1) sv += __shfl_xor(sv, o);
    if (lane == 0) wredB[wv] = sv;
    __syncthreads();                                      // S2
    float ssum = 0.0f;
    #pragma unroll
    for (int i = 0; i < 8; ++i) ssum += wredB[i];
    if (t < cnt) ea[t] = ex / (ssum + 1e-16f);
    __syncthreads();                                      // S3
    {
      int n0 = wv*20;
      int n1 = n0 + 20; if (n1 > cnt) n1 = cnt;
      float r = 0.0f;
      for (int n = n0; n < n1; ++n)
        r = fmaf(ea[n], hc[n*65 + lane], r);
      rsp[wv][lane] = r;
    }
    __syncthreads();                                      // S4
    if (t < 64){
      float r = rsp[0][t] + rsp[1][t] + rsp[2][t] + rsp[3][t]
              + rsp[4][t] + rsp[5][t] + rsp[6][t] + rsp[7][t];
      rsb[t] = r;
      x[t]        = hsb[t];
      x[64 + t]   = r;
      x[128 + t]  = hsb[t];
    }
    __syncthreads();                                      // S5
    {
      int gate = t & 255;
      int half = t >> 8;
      float gl = 0.0f;
      if (half == 0){
        const float* wr = Wli + (size_t)gate*128;
        for (int jj = 0; jj < 96; ++jj) gl = fmaf(x[jj], wr[jj], gl);
      } else {
        const float* wr = Wli + (size_t)gate*128;
        for (int jj = 96; jj < 128; ++jj) gl = fmaf(x[jj], wr[jj], gl);
        const float* wh = Wlh + (size_t)gate*64;
        for (int jj = 0; jj < 64; ++jj) gl = fmaf(x[128 + jj], wh[jj], gl);
      }
      gpart[t] = gl;
    }
    __syncthreads();                                      // S6
    if (t < 64){
      float iv = sigf (gpart[t]       + gpart[t + 256]       + bli[t]       + blh[t]);
      float fv = sigf (gpart[64 + t]  + gpart[64 + t + 256]  + bli[64 + t]  + blh[64 + t]);
      float gv = tanhf(gpart[128 + t] + gpart[128 + t + 256] + bli[128 + t] + blh[128 + t]);
      float ov = sigf (gpart[192 + t] + gpart[192 + t + 256] + bli[192 + t] + blh[192 + t]);
      float c  = fv*csb[t] + iv*gv;
      csb[t] = c;
      hsb[t] = ov*tanhf(c);
    }
    __syncthreads();                                      // S7
  }
  float rv = 0.0f;
  if (t < 64){
    float v = bm1[t];
    for (int j = 0; j < 64; ++j) v = fmaf(hsb[j], Wm1[(size_t)j*64 + t],        v);
    for (int j = 0; j < 64; ++j) v = fmaf(rsb[j], Wm1[(size_t)(64 + j)*64 + t], v);
    v = fmaxf(v, 0.0f);
    rv = v * Wm2[t];
  }
  for (int o = 32; o > 0; o >>= 1) rv += __shfl_xor(rv, o);
  if (lane == 0) wredA[wv] = rv;
  __syncthreads();
  if (t == 0) out[g] = wredA[0] + wredA[1] + wredA[2] + wredA[3]
                     + wredA[4] + wredA[5] + wredA[6] + wredA[7] + bm2[0];
}

extern "C" void kernel_launch(void* const* d_in, const int* in_sizes, int n_in,
                              void* d_out, int out_size, void* d_ws, size_t ws_size,
                              hipStream_t stream){
  (void)in_sizes; (void)n_in; (void)out_size;

  const float* nf  = (const float*)d_in[0];
  const float* ef  = (const float*)d_in[1];
  const int*   ei  = (const int*)d_in[2];
  const float* Wp  = (const float*)d_in[4];
  const float* bp  = (const float*)d_in[5];
  const float* We1 = (const float*)d_in[6];
  const float* be1 = (const float*)d_in[7];
  const float* We2 = (const float*)d_in[8];
  const float* be2 = (const float*)d_in[9];
  const float* Wg  = (const float*)d_in[10];
  const float* Wh  = (const float*)d_in[11];
  const float* bg  = (const float*)d_in[12];
  const float* bhb = (const float*)d_in[13];
  const float* Wli = (const float*)d_in[14];
  const float* Wlh = (const float*)d_in[15];
  const float* bli = (const float*)d_in[16];
  const float* blh = (const float*)d_in[17];
  const float* Wm1 = (const float*)d_in[18];
  const float* bm1 = (const float*)d_in[19];
  const float* Wm2 = (const float*)d_in[20];
  const float* bm2 = (const float*)d_in[21];

  float* out = (float*)d_out;
  float* ws  = (float*)d_ws;

  float* h    = ws;                         //   640000
  float* m    = ws + 640000;                //   640000
  float* bh   = ws + 1280000;               //   640000
  float* Mm   = ws + 1920000;               //   524288  (fallback)
  float* WgT  = ws + 2444288;               //    12288
  float* WhT  = ws + 2456576;               //    12288
  float* Hid  = ws + 2468864;               //  6400000 (fp32 fallback / fp16 main)
  half_t* Hid16 = (half_t*)Hid;
  int*   deg    = (int*)(ws + 8868864);
  int*   rowptr = deg + 10000;
  int*   cursor = rowptr + 10001;
  int*   csr    = cursor + 10000;
  half_t* AT  = (half_t*)(ws + 8948880);
  half_t* BT  = (half_t*)(ws + 9268880);
  const size_t C_OFF = 9531024;             // floats
  half_t* C   = (half_t*)(ws + C_OFF);

  long long c_halves = ((long long)ws_size - (long long)C_OFF*4) / 2;
  int NC = (c_halves > 0) ? (int)(c_halves / 8192) : 0;
  if (NC > N_NODES) NC = N_NODES;
  int use_c_path = (NC >= 512);
  int use_mfma   = (NC >= N_NODES);   // mfma path no longer needs C, but keep
                                      // the proven ws-size gate

  k_proj<<<(N_NODES*HID + 255)/256, 256, 0, stream>>>(nf, Wp, bp, h);

  if (use_c_path){
    k_twg <<<(192*64 + 255)/256, 256, 0, stream>>>(Wg, Wh, WgT, WhT);
    k_zero<<<(10000 + 255)/256, 256, 0, stream>>>((float*)deg, 10000);
    k_hist<<<(N_EDGES + 255)/256, 256, 0, stream>>>(ei, deg);
    k_scan<<<1, 256, 0, stream>>>(deg, rowptr, cursor);
    k_scatter<<<(N_EDGES + 255)/256, 256, 0, stream>>>(ei, cursor, csr);
    if (use_mfma){
      k_ehid16<<<(N_EDGES*EHID + 255)/256, 256, 0, stream>>>(ef, We1, be1, Hid16);
      k_w2bt<<<(512*2*64*8 + 255)/256, 256, 0, stream>>>(We2, BT);
      for (int step = 0; step < T_STEPS; ++step){
        k_prep<<<(N_NODES*HID + 255)/256, 256, 0, stream>>>(h, be2, m, bh, AT);
        dim3 grid(1250, 4);
        MPNN_55705725829535_kernel<<<grid, 256, 0, stream>>>(
            AT, BT, rowptr, csr, ei, Hid16, bh, m);
        k_gru<<<625, 256, 0, stream>>>(h, m, WgT, WhT, bg, bhb);
      }
    } else {
      k_ehid<<<(N_EDGES*EHID + 255)/256, 256, 0, stream>>>(ef, We1, be1, Hid);
      k_tw2<<<(64*8192)/256, 256, 0, stream>>>(We2, Mm);
      for (int step = 0; step < T_STEPS; ++step){
        k_zero<<<(N_NODES*HID + 255)/256, 256, 0, stream>>>(m, N_NODES*HID);
        k_bh<<<(N_NODES*HID + 255)/256, 256, 0, stream>>>(h, be2, bh);
        for (int lo = 0; lo < N_NODES; lo += NC){
          int hi = (lo + NC < N_NODES) ? lo + NC : N_NODES;
          int cnt = hi - lo;
          dim3 grid((cnt + 15)/16, 16);
          k_cgemm<<<grid, 256, 0, stream>>>(h, Mm, C, lo, hi);
          k_msg_csr<<<(cnt + 3)/4, 256, 0, stream>>>(
              rowptr, csr, ei, Hid, C, bh, m, lo, hi);
        }
        k_gru<<<625, 256, 0, stream>>>(h, m, WgT, WhT, bg, bhb);
      }
    }
  } else {
    k_twg <<<(192*64 + 255)/256, 256, 0, stream>>>(Wg, Wh, WgT, WhT);
    for (int step = 0; step < T_STEPS; ++step){
      k_zero<<<(N_NODES*HID + 255)/256, 256, 0, stream>>>(m, N_NODES*HID);
      k_msg_fb<<<N_EDGES, 64, 0, stream>>>(ei, ef, We1, be1, We2, be2, h, m);
      k_gru<<<625, 256, 0, stream>>>(h, m, WgT, WhT, bg, bhb);
    }
  }
  k_s2s<<<N_GRAPHS, 512, 0, stream>>>(h, Wli, Wlh, bli, blh,
                                      Wm1, bm1, Wm2, bm2, out);
}

// Round 6
// 580.777 us; speedup vs baseline: 1.2814x; 1.0032x over previous
//
#include <hip/hip_runtime.h>

#define N_NODES   10000
#define N_EDGES   50000
#define N_GRAPHS  64
#define NODE_DIM  32
#define EDGE_DIM  16
#define HID       64
#define EHID      128
#define T_STEPS   3
#define S2S_STEPS 6

typedef _Float16 half_t;
typedef _Float16 f16x8 __attribute__((ext_vector_type(8)));
typedef float    f32x4 __attribute__((ext_vector_type(4)));

__device__ __forceinline__ float sigf(float x){ return 1.0f/(1.0f + expf(-x)); }

__global__ void k_zero(float* p, int n){
  int i = blockIdx.x*256 + threadIdx.x;
  if (i < n) p[i] = 0.0f;
}

// h = nf @ W_proj + b_proj   (N x 64)
__global__ void k_proj(const float* __restrict__ nf, const float* __restrict__ Wp,
                       const float* __restrict__ bp, float* __restrict__ h){
  int idx = blockIdx.x*256 + threadIdx.x;
  if (idx >= N_NODES*HID) return;
  int n = idx >> 6;
  int c = idx & 63;
  float acc = bp[c];
  const float* row = nf + (size_t)n*NODE_DIM;
  for (int j = 0; j < NODE_DIM; ++j)
    acc = fmaf(row[j], Wp[j*HID + c], acc);
  h[idx] = acc;
}

// Mm (fp32, fallback path)
__global__ void k_tw2(const float* __restrict__ W2, float* __restrict__ Mm){
  int idx = blockIdx.x*256 + threadIdx.x;
  if (idx >= 64*8192) return;
  int j = idx >> 13; int o = idx & 8191; int k = o >> 6; int i = o & 63;
  Mm[idx] = W2[(size_t)k*4096 + i*64 + j];
}

// BT: W2 in MFMA B-fragment order (fp16), built once.
// BT[tn][tk][lane][j] : contraction k = tk*32 + (lane>>4)*8 + j (h-feature),
// output col o = tn*16 + (lane&15), o = k_edge*64 + i.
__global__ void k_w2bt(const float* __restrict__ W2, half_t* __restrict__ BT){
  int idx = blockIdx.x*256 + threadIdx.x;
  if (idx >= 512*2*64*8) return;
  int j    = idx & 7;
  int lane = (idx >> 3) & 63;
  int tk   = (idx >> 9) & 1;
  int tn   = idx >> 10;
  int k = tk*32 + ((lane >> 4) << 3) + j;
  int o = tn*16 + (lane & 15);
  BT[idx] = (half_t)W2[(size_t)(o >> 6)*4096 + (o & 63)*64 + k];
}

// AT: h in MFMA A-fragment order (fp16), per step (standalone, kept for clarity).
__global__ void k_h2a(const float* __restrict__ h, half_t* __restrict__ AT){
  int idx = blockIdx.x*256 + threadIdx.x;
  if (idx >= 625*2*64*8) return;
  int j    = idx & 7;
  int lane = (idx >> 3) & 63;
  int tk   = (idx >> 9) & 1;
  int tm   = idx >> 10;
  int mrow = tm*16 + (lane & 15);
  int k    = tk*32 + ((lane >> 4) << 3) + j;
  AT[idx] = (half_t)h[(size_t)mrow*64 + k];
}

// Fused per-step prep: m=0, bh = be2-rowdot(h), AT = h in A-fragment order.
__global__ void k_prep(const float* __restrict__ h, const float* __restrict__ be2,
                       float* __restrict__ m, float* __restrict__ bhp,
                       half_t* __restrict__ AT){
  int idx = blockIdx.x*256 + threadIdx.x;
  if (idx >= N_NODES*HID) return;
  m[idx] = 0.0f;
  int n = idx >> 6, i = idx & 63;
  float acc = 0.0f;
  const float* row = be2 + (size_t)i*64;
  const float* hr  = h + (size_t)n*64;
  for (int j = 0; j < 64; ++j)
    acc = fmaf(row[j], hr[j], acc);
  bhp[idx] = acc;
  int j    = idx & 7;
  int lane = (idx >> 3) & 63;
  int tk   = (idx >> 9) & 1;
  int tm   = idx >> 10;
  int mrow = tm*16 + (lane & 15);
  int k    = tk*32 + ((lane >> 4) << 3) + j;
  AT[idx] = (half_t)h[(size_t)mrow*64 + k];
}

// GRU weight transposes
__global__ void k_twg(const float* __restrict__ Wg, const float* __restrict__ Wh,
                      float* __restrict__ WgT, float* __restrict__ WhT){
  int idx = blockIdx.x*256 + threadIdx.x;
  if (idx >= 192*64) return;
  int row = idx >> 6;
  int j   = idx & 63;
  WgT[j*192 + row] = Wg[(size_t)row*64 + j];
  WhT[j*192 + row] = Wh[(size_t)row*64 + j];
}

// Hid = relu(ef @ W_e1 + b_e1)  fp32 (fallback path)
__global__ void k_ehid(const float* __restrict__ ef, const float* __restrict__ W1,
                       const float* __restrict__ b1, float* __restrict__ Hid){
  int idx = blockIdx.x*256 + threadIdx.x;
  if (idx >= N_EDGES*EHID) return;
  int e = idx >> 7, c = idx & 127;
  float acc = b1[c];
  const float* er = ef + (size_t)e*EDGE_DIM;
  for (int j = 0; j < EDGE_DIM; ++j)
    acc = fmaf(er[j], W1[j*EHID + c], acc);
  Hid[idx] = fmaxf(acc, 0.0f);
}

// Hid16 = relu(ef @ W_e1 + b_e1) in fp16 (MFMA message path)
__global__ void k_ehid16(const float* __restrict__ ef, const float* __restrict__ W1,
                         const float* __restrict__ b1, half_t* __restrict__ Hid16){
  int idx = blockIdx.x*256 + threadIdx.x;
  if (idx >= N_EDGES*EHID) return;
  int e = idx >> 7, c = idx & 127;
  float acc = b1[c];
  const float* er = ef + (size_t)e*EDGE_DIM;
  for (int j = 0; j < EDGE_DIM; ++j)
    acc = fmaf(er[j], W1[j*EHID + c], acc);
  Hid16[idx] = (half_t)fmaxf(acc, 0.0f);
}

// bh[n,i] = sum_j be2[i*64+j] * h[n,j]  (fallback path)
__global__ void k_bh(const float* __restrict__ h, const float* __restrict__ be2,
                     float* __restrict__ bh){
  int idx = blockIdx.x*256 + threadIdx.x;
  if (idx >= N_NODES*HID) return;
  int n = idx >> 6, i = idx & 63;
  float acc = 0.0f;
  const float* row = be2 + (size_t)i*64;
  const float* hr  = h + (size_t)n*64;
  for (int j = 0; j < 64; ++j)
    acc = fmaf(row[j], hr[j], acc);
  bh[idx] = acc;
}

// ---- CSR by src ----
__global__ void k_hist(const int* __restrict__ ei, int* __restrict__ deg){
  int e = blockIdx.x*256 + threadIdx.x;
  if (e >= N_EDGES) return;
  atomicAdd(&deg[ei[N_EDGES + e]], 1);
}

__global__ void k_scan(const int* __restrict__ deg, int* __restrict__ rowptr,
                       int* __restrict__ cursor){
  __shared__ int part[256];
  int t = threadIdx.x;
  int base = t*40;
  int s = 0;
  for (int i = 0; i < 40; ++i){
    int idx = base + i;
    if (idx < N_NODES) s += deg[idx];
  }
  part[t] = s;
  __syncthreads();
  for (int off = 1; off < 256; off <<= 1){
    int v = (t >= off) ? part[t - off] : 0;
    __syncthreads();
    part[t] += v;
    __syncthreads();
  }
  int run = (t > 0) ? part[t - 1] : 0;
  for (int i = 0; i < 40; ++i){
    int idx = base + i;
    if (idx < N_NODES){
      rowptr[idx] = run;
      cursor[idx] = run;
      run += deg[idx];
    }
  }
  if (t == 255) rowptr[N_NODES] = run;
}

__global__ void k_scatter(const int* __restrict__ ei, int* __restrict__ cursor,
                          int* __restrict__ csr){
  int e = blockIdx.x*256 + threadIdx.x;
  if (e >= N_EDGES) return;
  int src = ei[N_EDGES + e];
  int pos = atomicAdd(&cursor[src], 1);
  csr[pos] = e;
}

// ---- FUSED cgemm + message kernel (mfma path) ----
// r6: split the K dimension across blocks instead of duplicating A-rows (r5
// mistake: 2x blocks with full phase-1 chain each = 2x total work, occupancy
// gain eaten exactly). Block (tm, q, kh): C-slice for 16 nodes x 64 k (kh
// half) x 16 i (q quarter) in 33KB LDS -> 4 blocks/CU, phase-1 chain HALVED
// (32 MFMA + ~34 loads/wave). Chip-wide phase-1 work == r4. Messages are
// additive over k, so each kh-block atomicAdds its partial contraction
// (atomics 2x -> ~6.4M/dispatch, ~10us of TCC throughput — affordable).
// bh added only by kh==0.
__global__ void MPNN_55705725829535_kernel(const half_t* __restrict__ AT,
                                           const half_t* __restrict__ BT,
                                           const int* __restrict__ rowptr,
                                           const int* __restrict__ csr,
                                           const int* __restrict__ ei,
                                           const half_t* __restrict__ Hid16,
                                           const float* __restrict__ bh,
                                           float* __restrict__ m){
  __shared__ half_t Ct[16][2][520];
  __shared__ int dstW[4][16];
  int wv   = threadIdx.x >> 6;
  int lane = threadIdx.x & 63;
  int quad = lane >> 4;
  int colb = lane & 15;
  int tm = blockIdx.x;           // 0..624  (16-node tile)
  int q  = blockIdx.y;           // 0..3    (i-quarter)
  int kh = blockIdx.z;           // 0..1    (k-half)

  // ---- phase 1: C-slice GEMM into LDS (2 kt, 32 MFMA/wave) ----
  const f16x8* Ab = (const f16x8*)AT + (size_t)tm*128;
  f16x8 a0 = Ab[lane];
  f16x8 a1 = Ab[64 + lane];
  #pragma unroll
  for (int ktl = 0; ktl < 2; ++ktl){
    int kt = kh*2 + ktl;
    f32x4 acc[8];
    #pragma unroll
    for (int jj = 0; jj < 8; ++jj){
      acc[jj][0]=0.f; acc[jj][1]=0.f; acc[jj][2]=0.f; acc[jj][3]=0.f;
    }
    #pragma unroll
    for (int jj = 0; jj < 8; ++jj){
      int ke = kt*32 + wv*8 + jj;
      int tn = ke*4 + q;
      const f16x8* Bb = (const f16x8*)BT + (size_t)tn*128;
      acc[jj] = __builtin_amdgcn_mfma_f32_16x16x32_f16(a0, Bb[lane],      acc[jj], 0, 0, 0);
      acc[jj] = __builtin_amdgcn_mfma_f32_16x16x32_f16(a1, Bb[64 + lane], acc[jj], 0, 0, 0);
    }
    #pragma unroll
    for (int r = 0; r < 4; ++r){
      int node = quad*4 + r;       // 0..15
      f16x8 v;
      #pragma unroll
      for (int jj = 0; jj < 8; ++jj) v[jj] = (half_t)acc[jj][r];
      *(f16x8*)&Ct[node][ktl][(wv*16 + colb)*8] = v;
    }
  }
  __syncthreads();

  // ---- phase 2: partial message MFMAs (k-half), 4 nodes per wave ----
  for (int c = 0; c < 4; ++c){
    int node = wv*4 + c;           // 0..15
    int s = tm*16 + node;          // 625*16 == 10000 exactly
    int beg  = rowptr[s];
    int endp = rowptr[s + 1];
    if (beg == endp) continue;
    f16x8 B0 = *(const f16x8*)&Ct[node][0][lane*8];
    f16x8 B1 = *(const f16x8*)&Ct[node][1][lane*8];
    float bhc = (kh == 0) ? bh[(size_t)s*64 + q*16 + colb] : 0.0f;
    for (int gbeg = beg; gbeg < endp; gbeg += 16){
      int gn = endp - gbeg; if (gn > 16) gn = 16;
      if (lane < 16)
        dstW[wv][lane] = (lane < gn) ? ei[csr[gbeg + lane]] : -1;
      f16x8 A0, A1;
      if (colb < gn){
        int e = csr[gbeg + colb];
        const f16x8* Hb = (const f16x8*)(Hid16 + (size_t)e*128) + quad;
        A0 = Hb[(kh*2 + 0)*4];
        A1 = Hb[(kh*2 + 1)*4];
      } else {
        #pragma unroll
        for (int p = 0; p < 8; ++p){ A0[p] = (half_t)0; A1[p] = (half_t)0; }
      }
      f32x4 acc;
      acc[0]=0.f; acc[1]=0.f; acc[2]=0.f; acc[3]=0.f;
      acc = __builtin_amdgcn_mfma_f32_16x16x32_f16(A0, B0, acc, 0, 0, 0);
      acc = __builtin_amdgcn_mfma_f32_16x16x32_f16(A1, B1, acc, 0, 0, 0);
      #pragma unroll
      for (int r = 0; r < 4; ++r){
        int jrow = quad*4 + r;
        if (jrow < gn){
          int d = dstW[wv][jrow];
          atomicAdd(&m[(size_t)d*64 + q*16 + colb], acc[r] + bhc);
        }
      }
    }
  }
}

// scalar cgemm (fallback, chunked): 2 cols/thread, fp16 stores, OLD linear C layout
__global__ void k_cgemm(const float* __restrict__ h, const float* __restrict__ Mm,
                        half_t* __restrict__ C, int lo, int hi){
  __shared__ float hs[16][64];
  int n0 = lo + blockIdx.x*16;
  int o0 = blockIdx.y*256 + threadIdx.x;
  for (int idx = threadIdx.x; idx < 16*64; idx += 256){
    int nn = idx >> 6, j = idx & 63;
    int node = n0 + nn;
    hs[nn][j] = (node < hi) ? h[(size_t)node*64 + j] : 0.0f;
  }
  __syncthreads();
  float acc0[16], acc1[16];
  #pragma unroll
  for (int nn = 0; nn < 16; ++nn){ acc0[nn] = 0.0f; acc1[nn] = 0.0f; }
  for (int j4 = 0; j4 < 16; ++j4){
    const float* M0 = Mm + (size_t)(j4*4)*8192;
    float a0 = M0[o0],            b0 = M0[o0 + 4096];
    float a1 = M0[8192 + o0],     b1 = M0[8192 + o0 + 4096];
    float a2 = M0[2*8192 + o0],   b2 = M0[2*8192 + o0 + 4096];
    float a3 = M0[3*8192 + o0],   b3 = M0[3*8192 + o0 + 4096];
    #pragma unroll
    for (int nn = 0; nn < 16; ++nn){
      float4 hv = *(const float4*)&hs[nn][j4*4];
      acc0[nn] = fmaf(hv.x, a0, acc0[nn]);
      acc1[nn] = fmaf(hv.x, b0, acc1[nn]);
      acc0[nn] = fmaf(hv.y, a1, acc0[nn]);
      acc1[nn] = fmaf(hv.y, b1, acc1[nn]);
      acc0[nn] = fmaf(hv.z, a2, acc0[nn]);
      acc1[nn] = fmaf(hv.z, b2, acc1[nn]);
      acc0[nn] = fmaf(hv.w, a3, acc0[nn]);
      acc1[nn] = fmaf(hv.w, b3, acc1[nn]);
    }
  }
  #pragma unroll
  for (int nn = 0; nn < 16; ++nn){
    int node = n0 + nn;
    if (node < hi){
      half_t* Cr = C + (size_t)(node - lo)*8192;
      Cr[o0]        = (half_t)acc0[nn];
      Cr[o0 + 4096] = (half_t)acc1[nn];
    }
  }
}

// old-style streaming msg kernel (fallback path, fp32 Hid, OLD linear C layout)
__global__ void k_msg_csr(const int* __restrict__ rowptr,
                          const int* __restrict__ csr,
                          const int* __restrict__ ei,
                          const float* __restrict__ Hid,
                          const half_t* __restrict__ C,
                          const float* __restrict__ bh,
                          float* __restrict__ m, int lo, int hi){
  __shared__ float hidL[4][8][128];
  int wave = threadIdx.x >> 6;
  int lane = threadIdx.x & 63;
  int s = lo + blockIdx.x*4 + wave;
  if (s >= hi) return;
  int beg = rowptr[s];
  int endp = rowptr[s + 1];
  if (beg == endp) return;
  float bhv = bh[(size_t)s*64 + lane];
  const half_t* Cb = C + (size_t)(s - lo)*8192 + lane;
  float (*hl)[128] = hidL[wave];
  for (int gbeg = beg; gbeg < endp; gbeg += 8){
    int gn = endp - gbeg; if (gn > 8) gn = 8;
    int dsts[8];
    int e0 = csr[gbeg];
    #pragma unroll
    for (int j = 0; j < 8; ++j){
      int e = (j < gn) ? csr[gbeg + j] : e0;
      dsts[j] = ei[e];
      hl[j][lane]      = Hid[(size_t)e*128 + lane];
      hl[j][lane + 64] = Hid[(size_t)e*128 + 64 + lane];
    }
    float acc[8];
    #pragma unroll
    for (int j = 0; j < 8; ++j) acc[j] = 0.0f;
    #pragma unroll 4
    for (int k = 0; k < 128; ++k){
      float c = (float)Cb[k*64];
      #pragma unroll
      for (int j = 0; j < 8; ++j)
        acc[j] = fmaf(hl[j][k], c, acc[j]);
    }
    for (int j = 0; j < gn; ++j)
      atomicAdd(&m[(size_t)dsts[j]*64 + lane], acc[j] + bhv);
  }
}

// fallback per-edge bilinear (only if ws too small for the C path)
__global__ void k_msg_fb(const int* __restrict__ ei, const float* __restrict__ ef,
                         const float* __restrict__ W1, const float* __restrict__ b1,
                         const float* __restrict__ W2, const float* __restrict__ be2,
                         const float* __restrict__ h, float* __restrict__ m){
  __shared__ float HidL[EHID];
  __shared__ __align__(16) float hsL[HID];
  int e = blockIdx.x;
  int t = threadIdx.x;
  int src = ei[N_EDGES + e];
  int dst = ei[e];
  {
    float a0 = b1[t];
    float a1 = b1[t + 64];
    const float* er = ef + (size_t)e*EDGE_DIM;
    for (int j = 0; j < EDGE_DIM; ++j){
      float ev = er[j];
      a0 = fmaf(ev, W1[j*EHID + t],      a0);
      a1 = fmaf(ev, W1[j*EHID + t + 64], a1);
    }
    HidL[t]      = fmaxf(a0, 0.0f);
    HidL[t + 64] = fmaxf(a1, 0.0f);
    hsL[t] = h[(size_t)src*64 + t];
  }
  __syncthreads();
  float acc = 0.0f;
  for (int k = 0; k < EHID; ++k){
    float s = HidL[k];
    if (s != 0.0f){
      const float* w = W2 + (size_t)k*4096 + t*64;
      float partial = 0.0f;
      for (int j = 0; j < 64; ++j)
        partial = fmaf(hsL[j], w[j], partial);
      acc = fmaf(s, partial, acc);
    }
  }
  {
    const float* w = be2 + (size_t)t*64;
    for (int j = 0; j < 64; ++j)
      acc = fmaf(hsL[j], w[j], acc);
  }
  atomicAdd(&m[(size_t)dst*64 + t], acc);
}

// GRU: 256 threads = 4 waves, 16 nodes/block (4 per wave).
__global__ void k_gru(float* __restrict__ h, const float* __restrict__ m,
                      const float* __restrict__ WgT, const float* __restrict__ WhT,
                      const float* __restrict__ bg, const float* __restrict__ bhb){
  __shared__ float mld[16][64];
  __shared__ float hld[16][64];
  int t  = threadIdx.x;
  int i  = t & 63;
  int wv = t >> 6;                  // 0..3
  int n0 = blockIdx.x*16;           // 625*16 == 10000 exactly
  for (int idx = t; idx < 16*64; idx += 256){
    int nn = idx >> 6, j = idx & 63;
    int node = n0 + nn;
    mld[nn][j] = m[(size_t)node*64 + j];
    hld[nn][j] = h[(size_t)node*64 + j];
  }
  __syncthreads();
  float xr[4], xz[4], xn[4], hr[4], hz[4], hn[4];
  #pragma unroll
  for (int c = 0; c < 4; ++c){
    xr[c] = bg[i];  xz[c] = bg[64 + i];  xn[c] = bg[128 + i];
    hr[c] = bhb[i]; hz[c] = bhb[64 + i]; hn[c] = bhb[128 + i];
  }
  for (int j = 0; j < 64; ++j){
    const float* wg = WgT + j*192;
    const float* wh = WhT + j*192;
    float wgr = wg[i], wgz = wg[64 + i], wgn = wg[128 + i];
    float whr = wh[i], whz = wh[64 + i], whn = wh[128 + i];
    #pragma unroll
    for (int c = 0; c < 4; ++c){
      int nn = wv*4 + c;
      float mj = mld[nn][j];
      float hj = hld[nn][j];
      xr[c] = fmaf(mj, wgr, xr[c]);
      xz[c] = fmaf(mj, wgz, xz[c]);
      xn[c] = fmaf(mj, wgn, xn[c]);
      hr[c] = fmaf(hj, whr, hr[c]);
      hz[c] = fmaf(hj, whz, hz[c]);
      hn[c] = fmaf(hj, whn, hn[c]);
    }
  }
  #pragma unroll
  for (int c = 0; c < 4; ++c){
    int nn = wv*4 + c;
    float r  = sigf(xr[c] + hr[c]);
    float z  = sigf(xz[c] + hz[c]);
    float nv = tanhf(xn[c] + r*hn[c]);
    h[(size_t)(n0 + nn)*64 + i] = (1.0f - z)*nv + z*hld[nn][i];
  }
}

// Set2Set + LSTM + readout; 512 threads: rsb 8-way split, gates 2-way split.
// Direct Wli/Wlh reads (per-thread sequential rows vectorize to dwordx4 and
// L1-hit; r1's coalesced-WcT layout REGRESSED 56->95us — do not retry).
__global__ void k_s2s(const float* __restrict__ h,
                      const float* __restrict__ Wli, const float* __restrict__ Wlh,
                      const float* __restrict__ bli, const float* __restrict__ blh,
                      const float* __restrict__ Wm1, const float* __restrict__ bm1,
                      const float* __restrict__ Wm2, const float* __restrict__ bm2,
                      float* __restrict__ out){
  __shared__ float hc[157*65];
  __shared__ float ea[160];
  __shared__ float x[192];
  __shared__ float gpart[512];
  __shared__ float rsp[8][64];
  __shared__ float wredA[8];
  __shared__ float wredB[8];
  __shared__ float hsb[64];
  __shared__ float csb[64];
  __shared__ float rsb[64];
  int g = blockIdx.x;
  int t = threadIdx.x;          // 0..511
  int lane = t & 63;
  int wv   = t >> 6;            // 0..7
  int start = (g*N_NODES + 63) >> 6;
  int end   = ((g + 1)*N_NODES + 63) >> 6;
  int cnt = end - start;        // 156 or 157
  const float* hg = h + (size_t)start*64;
  for (int idx = t; idx < cnt*64; idx += 512)
    hc[(idx >> 6)*65 + (idx & 63)] = hg[idx];
  if (t < 64){ hsb[t] = 0.0f; csb[t] = 0.0f; rsb[t] = 0.0f; }
  __syncthreads();
  for (int step = 0; step < S2S_STEPS; ++step){
    float ev = -1e30f;
    if (t < cnt){
      float a = 0.0f;
      const float* hr = &hc[t*65];
      for (int i = 0; i < 64; ++i) a = fmaf(hr[i], hsb[i], a);
      ev = a;
    }
    float v = ev;
    for (int o = 32; o > 0; o >>= 1) v = fmaxf(v, __shfl_xor(v, o));
    if (lane == 0) wredA[wv] = v;
    __syncthreads();                                      // S1
    float mx = wredA[0];
    #pragma unroll
    for (int i = 1; i < 8; ++i) mx = fmaxf(mx, wredA[i]);
    float ex = (t < cnt) ? expf(ev - mx) : 0.0f;
    float sv = ex;
    for (int o = 32; o > 0; o >>= 1) sv += __shfl_xor(sv, o);
    if (lane == 0) wredB[wv] = sv;
    __syncthreads();                                      // S2
    float ssum = 0.0f;
    #pragma unroll
    for (int i = 0; i < 8; ++i) ssum += wredB[i];
    if (t < cnt) ea[t] = ex / (ssum + 1e-16f);
    __syncthreads();                                      // S3
    {
      int n0 = wv*20;
      int n1 = n0 + 20; if (n1 > cnt) n1 = cnt;
      float r = 0.0f;
      for (int n = n0; n < n1; ++n)
        r = fmaf(ea[n], hc[n*65 + lane], r);
      rsp[wv][lane] = r;
    }
    __syncthreads();                                      // S4
    if (t < 64){
      float r = rsp[0][t] + rsp[1][t] + rsp[2][t] + rsp[3][t]
              + rsp[4][t] + rsp[5][t] + rsp[6][t] + rsp[7][t];
      rsb[t] = r;
      x[t]        = hsb[t];
      x[64 + t]   = r;
      x[128 + t]  = hsb[t];
    }
    __syncthreads();                                      // S5
    {
      int gate = t & 255;
      int half = t >> 8;
      float gl = 0.0f;
      if (half == 0){
        const float* wr = Wli + (size_t)gate*128;
        for (int jj = 0; jj < 96; ++jj) gl = fmaf(x[jj], wr[jj], gl);
      } else {
        const float* wr = Wli + (size_t)gate*128;
        for (int jj = 96; jj < 128; ++jj) gl = fmaf(x[jj], wr[jj], gl);
        const float* wh = Wlh + (size_t)gate*64;
        for (int jj = 0; jj < 64; ++jj) gl = fmaf(x[128 + jj], wh[jj], gl);
      }
      gpart[t] = gl;
    }
    __syncthreads();                                      // S6
    if (t < 64){
      float iv = sigf (gpart[t]       + gpart[t + 256]       + bli[t]       + blh[t]);
      float fv = sigf (gpart[64 + t]  + gpart[64 + t + 256]  + bli[64 + t]  + blh[64 + t]);
      float gv = tanhf(gpart[128 + t] + gpart[128 + t + 256] + bli[128 + t] + blh[128 + t]);
      float ov = sigf (gpart[192 + t] + gpart[192 + t + 256] + bli[192 + t] + blh[192 + t]);
      float c  = fv*csb[t] + iv*gv;
      csb[t] = c;
      hsb[t] = ov*tanhf(c);
    }
    __syncthreads();                                      // S7
  }
  float rv = 0.0f;
  if (t < 64){
    float v = bm1[t];
    for (int j = 0; j < 64; ++j) v = fmaf(hsb[j], Wm1[(size_t)j*64 + t],        v);
    for (int j = 0; j < 64; ++j) v = fmaf(rsb[j], Wm1[(size_t)(64 + j)*64 + t], v);
    v = fmaxf(v, 0.0f);
    rv = v * Wm2[t];
  }
  for (int o = 32; o > 0; o >>= 1) rv += __shfl_xor(rv, o);
  if (lane == 0) wredA[wv] = rv;
  __syncthreads();
  if (t == 0) out[g] = wredA[0] + wredA[1] + wredA[2] + wredA[3]
                     + wredA[4] + wredA[5] + wredA[6] + wredA[7] + bm2[0];
}

extern "C" void kernel_launch(void* const* d_in, const int* in_sizes, int n_in,
                              void* d_out, int out_size, void* d_ws, size_t ws_size,
                              hipStream_t stream){
  (void)in_sizes; (void)n_in; (void)out_size;

  const float* nf  = (const float*)d_in[0];
  const float* ef  = (const float*)d_in[1];
  const int*   ei  = (const int*)d_in[2];
  const float* Wp  = (const float*)d_in[4];
  const float* bp  = (const float*)d_in[5];
  const float* We1 = (const float*)d_in[6];
  const float* be1 = (const float*)d_in[7];
  const float* We2 = (const float*)d_in[8];
  const float* be2 = (const float*)d_in[9];
  const float* Wg  = (const float*)d_in[10];
  const float* Wh  = (const float*)d_in[11];
  const float* bg  = (const float*)d_in[12];
  const float* bhb = (const float*)d_in[13];
  const float* Wli = (const float*)d_in[14];
  const float* Wlh = (const float*)d_in[15];
  const float* bli = (const float*)d_in[16];
  const float* blh = (const float*)d_in[17];
  const float* Wm1 = (const float*)d_in[18];
  const float* bm1 = (const float*)d_in[19];
  const float* Wm2 = (const float*)d_in[20];
  const float* bm2 = (const float*)d_in[21];

  float* out = (float*)d_out;
  float* ws  = (float*)d_ws;

  float* h    = ws;                         //   640000
  float* m    = ws + 640000;                //   640000
  float* bh   = ws + 1280000;               //   640000
  float* Mm   = ws + 1920000;               //   524288  (fallback)
  float* WgT  = ws + 2444288;               //    12288
  float* WhT  = ws + 2456576;               //    12288
  float* Hid  = ws + 2468864;               //  6400000 (fp32 fallback / fp16 main)
  half_t* Hid16 = (half_t*)Hid;
  int*   deg    = (int*)(ws + 8868864);
  int*   rowptr = deg + 10000;
  int*   cursor = rowptr + 10001;
  int*   csr    = cursor + 10000;
  half_t* AT  = (half_t*)(ws + 8948880);
  half_t* BT  = (half_t*)(ws + 9268880);
  const size_t C_OFF = 9531024;             // floats
  half_t* C   = (half_t*)(ws + C_OFF);

  long long c_halves = ((long long)ws_size - (long long)C_OFF*4) / 2;
  int NC = (c_halves > 0) ? (int)(c_halves / 8192) : 0;
  if (NC > N_NODES) NC = N_NODES;
  int use_c_path = (NC >= 512);
  int use_mfma   = (NC >= N_NODES);   // mfma path no longer needs C, but keep
                                      // the proven ws-size gate

  k_proj<<<(N_NODES*HID + 255)/256, 256, 0, stream>>>(nf, Wp, bp, h);

  if (use_c_path){
    k_twg <<<(192*64 + 255)/256, 256, 0, stream>>>(Wg, Wh, WgT, WhT);
    k_zero<<<(10000 + 255)/256, 256, 0, stream>>>((float*)deg, 10000);
    k_hist<<<(N_EDGES + 255)/256, 256, 0, stream>>>(ei, deg);
    k_scan<<<1, 256, 0, stream>>>(deg, rowptr, cursor);
    k_scatter<<<(N_EDGES + 255)/256, 256, 0, stream>>>(ei, cursor, csr);
    if (use_mfma){
      k_ehid16<<<(N_EDGES*EHID + 255)/256, 256, 0, stream>>>(ef, We1, be1, Hid16);
      k_w2bt<<<(512*2*64*8 + 255)/256, 256, 0, stream>>>(We2, BT);
      for (int step = 0; step < T_STEPS; ++step){
        k_prep<<<(N_NODES*HID + 255)/256, 256, 0, stream>>>(h, be2, m, bh, AT);
        dim3 grid(625, 4, 2);
        MPNN_55705725829535_kernel<<<grid, 256, 0, stream>>>(
            AT, BT, rowptr, csr, ei, Hid16, bh, m);
        k_gru<<<625, 256, 0, stream>>>(h, m, WgT, WhT, bg, bhb);
      }
    } else {
      k_ehid<<<(N_EDGES*EHID + 255)/256, 256, 0, stream>>>(ef, We1, be1, Hid);
      k_tw2<<<(64*8192)/256, 256, 0, stream>>>(We2, Mm);
      for (int step = 0; step < T_STEPS; ++step){
        k_zero<<<(N_NODES*HID + 255)/256, 256, 0, stream>>>(m, N_NODES*HID);
        k_bh<<<(N_NODES*HID + 255)/256, 256, 0, stream>>>(h, be2, bh);
        for (int lo = 0; lo < N_NODES; lo += NC){
          int hi = (lo + NC < N_NODES) ? lo + NC : N_NODES;
          int cnt = hi - lo;
          dim3 grid((cnt + 15)/16, 16);
          k_cgemm<<<grid, 256, 0, stream>>>(h, Mm, C, lo, hi);
          k_msg_csr<<<(cnt + 3)/4, 256, 0, stream>>>(
              rowptr, csr, ei, Hid, C, bh, m, lo, hi);
        }
        k_gru<<<625, 256, 0, stream>>>(h, m, WgT, WhT, bg, bhb);
      }
    }
  } else {
    k_twg <<<(192*64 + 255)/256, 256, 0, stream>>>(Wg, Wh, WgT, WhT);
    for (int step = 0; step < T_STEPS; ++step){
      k_zero<<<(N_NODES*HID + 255)/256, 256, 0, stream>>>(m, N_NODES*HID);
      k_msg_fb<<<N_EDGES, 64, 0, stream>>>(ei, ef, We1, be1, We2, be2, h, m);
      k_gru<<<625, 256, 0, stream>>>(h, m, WgT, WhT, bg, bhb);
    }
  }
  k_s2s<<<N_GRAPHS, 512, 0, stream>>>(h, Wli, Wlh, bli, blh,
                                      Wm1, bm1, Wm2, bm2, out);
}